// Round 4
// baseline (4645.167 us; speedup 1.0000x reference)
//
#include <hip/hip_runtime.h>

#define Bsz 512
#define Lsz 30
#define Hsz 1024
#define Tsz 30

typedef __bf16 bf16x8 __attribute__((ext_vector_type(8)));
typedef float  f32x4  __attribute__((ext_vector_type(4)));

__device__ __forceinline__ float bf2f(unsigned short s) {
  union { unsigned int u; float f; } v; v.u = ((unsigned int)s) << 16; return v.f;
}
__device__ __forceinline__ unsigned short f2bf(float f) {
  union { float f; unsigned int u; } v; v.f = f;
  return (unsigned short)((v.u + 0x7FFFu + ((v.u >> 16) & 1u)) >> 16);
}
__device__ __forceinline__ bf16x8 ld8u(const unsigned short* p) {
  return *reinterpret_cast<const bf16x8*>(p);
}

// ---------------- split fp32 -> (hi, lo) bf16 planes ---------------------------
__global__ __launch_bounds__(256) void k_split(
    const float* __restrict__ src, unsigned short* __restrict__ hi,
    unsigned short* __restrict__ lo, int n4)
{
  const int i = blockIdx.x * 256 + threadIdx.x;
  if (i >= n4) return;
  const float4 v = ((const float4*)src)[i];
  unsigned short h0 = f2bf(v.x), h1 = f2bf(v.y), h2 = f2bf(v.z), h3 = f2bf(v.w);
  unsigned short l0 = f2bf(v.x - bf2f(h0)), l1 = f2bf(v.y - bf2f(h1));
  unsigned short l2 = f2bf(v.z - bf2f(h2)), l3 = f2bf(v.w - bf2f(h3));
  ((ushort4*)hi)[i] = make_ushort4(h0, h1, h2, h3);
  ((ushort4*)lo)[i] = make_ushort4(l0, l1, l2, l3);
}

// ---------------- init: h0 = mean_L(input_hidden) + splits, masks --------------
__global__ __launch_bounds__(256) void k_init(
    const float* __restrict__ ih, const int* __restrict__ pos,
    float* __restrict__ hf, unsigned short* __restrict__ hh,
    unsigned short* __restrict__ hl,
    unsigned int* __restrict__ flag, unsigned int* __restrict__ valid)
{
  const int b = blockIdx.x;
  const float* base = ih + (size_t)b * Lsz * Hsz;
  #pragma unroll
  for (int i = 0; i < 4; ++i) {
    const int c = threadIdx.x + 256 * i;
    float s = 0.f;
    for (int l = 0; l < Lsz; ++l) s += base[l * Hsz + c];
    s /= 30.0f;
    const size_t o = (size_t)b * Hsz + c;
    hf[o] = s;
    const unsigned short h = f2bf(s);
    hh[o] = h; hl[o] = f2bf(s - bf2f(h));
  }
  if (threadIdx.x == 0) {
    int ss = 0;
    for (int l = 0; l < Lsz; ++l) ss += (pos[b * Lsz + l] != -1) ? 1 : 0;
    valid[b] = (ss >= 32) ? 0xFFFFFFFFu : ((1u << ss) - 1u);
    flag[b]  = 0u;
  }
}

// ---------------- gi0 = S @ W_ih^T (fp32 GEMV, 3072 outputs) -------------------
__global__ __launch_bounds__(256) void k_gemv0(
    const float* __restrict__ S, const float* __restrict__ wih,
    float* __restrict__ gi0)
{
  const int n = blockIdx.x * 64 + (threadIdx.x >> 2);
  const int part = threadIdx.x & 3;
  const float4* s4 = (const float4*)S + part * 64;
  const float4* w4 = (const float4*)(wih + (size_t)n * Hsz) + part * 64;
  float s = 0.f;
  #pragma unroll 8
  for (int i = 0; i < 64; ++i) {
    const float4 a = s4[i], b = w4[i];
    s = fmaf(a.x, b.x, s); s = fmaf(a.y, b.y, s);
    s = fmaf(a.z, b.z, s); s = fmaf(a.w, b.w, s);
  }
  s += __shfl_xor(s, 1, 64);
  s += __shfl_xor(s, 2, 64);
  if (part == 0) gi0[n] = s;
}

// ---------------- 3-pass split-bf16 GEMM: C[M,N] = A[M,K] @ B[N,K]^T -----------
// 256 threads, 64x64 tile, 2x2 waves of 32x32 (2x2 frags of 16x16), K=1024.
// GIMODE=1: A rows map to tgt[b][t0-1+chunkstep], C writes into 8-slot ring.
template<int GIMODE>
__global__ __launch_bounds__(256) void k_gemm3(
    const unsigned short* __restrict__ Ah, const unsigned short* __restrict__ Al,
    const unsigned short* __restrict__ Bh, const unsigned short* __restrict__ Bl,
    float* __restrict__ C, int ldc, const float* __restrict__ bias, int t0)
{
  const int nt = blockIdx.x * 64;
  const int mt = blockIdx.y * 64;
  const int w = threadIdx.x >> 6;
  const int wm = w >> 1, wn = w & 1;
  const int lane = threadIdx.x & 63;
  const int lr = lane & 15, lg = lane >> 4;

  const int r0 = mt + wm * 32 + lr;
  const int c0 = nt + wn * 32 + lr;

  size_t aoff[2], boff[2];
  #pragma unroll
  for (int m = 0; m < 2; ++m) {
    const int r = r0 + m * 16;
    if (GIMODE) aoff[m] = ((size_t)(r & 511) * Tsz + (t0 - 1) + (r >> 9)) * Hsz;
    else        aoff[m] = (size_t)r * Hsz;
  }
  #pragma unroll
  for (int nf = 0; nf < 2; ++nf) boff[nf] = (size_t)(c0 + nf * 16) * Hsz;

  f32x4 acc[2][2] = {};

  #pragma unroll 2
  for (int k0 = 0; k0 < Hsz; k0 += 32) {
    const int ko = k0 + lg * 8;
    bf16x8 ah[2], al[2], bh[2], bl[2];
    #pragma unroll
    for (int m = 0; m < 2; ++m) { ah[m] = ld8u(Ah + aoff[m] + ko); al[m] = ld8u(Al + aoff[m] + ko); }
    #pragma unroll
    for (int nf = 0; nf < 2; ++nf) { bh[nf] = ld8u(Bh + boff[nf] + ko); bl[nf] = ld8u(Bl + boff[nf] + ko); }
    #pragma unroll
    for (int m = 0; m < 2; ++m)
      #pragma unroll
      for (int nf = 0; nf < 2; ++nf) {
        acc[m][nf] = __builtin_amdgcn_mfma_f32_16x16x32_bf16(ah[m], bh[nf], acc[m][nf], 0, 0, 0);
        acc[m][nf] = __builtin_amdgcn_mfma_f32_16x16x32_bf16(ah[m], bl[nf], acc[m][nf], 0, 0, 0);
        acc[m][nf] = __builtin_amdgcn_mfma_f32_16x16x32_bf16(al[m], bh[nf], acc[m][nf], 0, 0, 0);
      }
  }

  #pragma unroll
  for (int nf = 0; nf < 2; ++nf) {
    const int c = c0 + nf * 16;
    const float bb = bias ? bias[c] : 0.f;
    #pragma unroll
    for (int m = 0; m < 2; ++m) {
      #pragma unroll
      for (int rr = 0; rr < 4; ++rr) {
        const int row = mt + wm * 32 + m * 16 + lg * 4 + rr;
        if (GIMODE) {
          const int slot = (t0 + (row >> 9)) & 7;
          C[((size_t)slot * Bsz + (row & 511)) * 3072 + c] = acc[m][nf][rr];
        } else {
          C[(size_t)row * ldc + c] = acc[m][nf][rr] + bb;
        }
      }
    }
  }
}

// ---------------- GRU combine: h_new from gi(ring), gh, biases -----------------
__global__ __launch_bounds__(256) void k_combine(
    const float* __restrict__ gh, const float* __restrict__ gi, int gistride,
    const float* __restrict__ bih, const float* __restrict__ bhh,
    const float* __restrict__ hf_in, float* __restrict__ hf_out,
    unsigned short* __restrict__ hh, unsigned short* __restrict__ hl)
{
  const int idx = blockIdx.x * 256 + threadIdx.x;
  const int b = idx >> 10, c = idx & 1023;
  const size_t g = (size_t)b * 3072;
  const size_t gg = (size_t)b * gistride;
  const float pr = gi[gg + c]            + bih[c]          + gh[g + c]            + bhh[c];
  const float pz = gi[gg + Hsz + c]      + bih[Hsz + c]    + gh[g + Hsz + c]      + bhh[Hsz + c];
  const float r = 1.f / (1.f + expf(-pr));
  const float z = 1.f / (1.f + expf(-pz));
  const float n = tanhf(gi[gg + 2*Hsz + c] + bih[2*Hsz + c] + r * (gh[g + 2*Hsz + c] + bhh[2*Hsz + c]));
  const float h = (1.f - z) * n + z * hf_in[idx];
  hf_out[idx] = h;
  const unsigned short hb = f2bf(h);
  hh[idx] = hb; hl[idx] = f2bf(h - bf2f(hb));
}

// ---------------- attention scores + masked softmax + argmax/flag + outputs ----
__global__ __launch_bounds__(256) void k_attn(
    const float* __restrict__ q, const float* __restrict__ ih,
    unsigned int* __restrict__ flag, const unsigned int* __restrict__ valid,
    float* __restrict__ out, int t)
{
  const int b = blockIdx.x;
  __shared__ float pre_s[32];
  __shared__ float top_s[32];
  const int w = threadIdx.x >> 6;
  const int lane = threadIdx.x & 63;

  float qr[16];
  const float4* q4 = (const float4*)(q + (size_t)b * Hsz);
  #pragma unroll
  for (int i = 0; i < 4; ++i) {
    const float4 v = q4[lane * 4 + i];
    qr[4*i+0] = v.x; qr[4*i+1] = v.y; qr[4*i+2] = v.z; qr[4*i+3] = v.w;
  }

  for (int l = w; l < Lsz; l += 4) {
    const float4* r4 = (const float4*)(ih + (size_t)b * Lsz * Hsz + (size_t)l * Hsz);
    float s = 0.f;
    #pragma unroll
    for (int i = 0; i < 4; ++i) {
      const float4 v = r4[lane * 4 + i];
      s = fmaf(qr[4*i+0], v.x, s);
      s = fmaf(qr[4*i+1], v.y, s);
      s = fmaf(qr[4*i+2], v.z, s);
      s = fmaf(qr[4*i+3], v.w, s);
    }
    #pragma unroll
    for (int off = 32; off >= 1; off >>= 1) s += __shfl_xor(s, off, 64);
    if (lane == 0) pre_s[l] = s;
  }
  __syncthreads();

  if (threadIdx.x == 0) {
    const unsigned int fl = flag[b];
    const unsigned int ex = fl | ~valid[b];
    float best = -3.4e38f; int am = 0;
    for (int l = 0; l < Lsz; ++l) {
      if (!((ex >> l) & 1u)) { const float v = pre_s[l]; if (v > best) { best = v; am = l; } }
    }
    float sum = 0.f;
    for (int l = 0; l < Lsz; ++l) {
      const float e = ((ex >> l) & 1u) ? 0.f : expf(pre_s[l] - best);
      top_s[l] = e; sum += e;
    }
    const float inv = 1.f / sum;
    for (int l = 0; l < Lsz; ++l) top_s[l] *= inv;
    flag[b] = fl | (1u << am);
  }
  __syncthreads();

  if (threadIdx.x < Lsz) {
    const int l = threadIdx.x;
    out[(size_t)b * (Tsz * Lsz) + t * Lsz + l] = pre_s[l];
    out[(size_t)Bsz * Tsz * Lsz + (size_t)b * (Tsz * Lsz) + t * Lsz + l] = top_s[l];
  }
}

extern "C" void kernel_launch(void* const* d_in, const int* in_sizes, int n_in,
                              void* d_out, int out_size, void* d_ws, size_t ws_size,
                              hipStream_t stream) {
  const float* ih  = (const float*)d_in[0];
  const float* tg  = (const float*)d_in[1];
  const int*   pos = (const int*)d_in[2];
  const float* S   = (const float*)d_in[4];
  const float* wih = (const float*)d_in[5];
  const float* whh = (const float*)d_in[6];
  const float* bih = (const float*)d_in[7];
  const float* bhh = (const float*)d_in[8];
  const float* wlw = (const float*)d_in[9];
  const float* wlb = (const float*)d_in[10];
  float* out = (float*)d_out;

  const size_t NX  = (size_t)Bsz * Tsz * Hsz;   // 15.7M
  const size_t NW3 = (size_t)3 * Hsz * Hsz;     // 3.1M
  const size_t NW1 = (size_t)Hsz * Hsz;         // 1M
  const size_t NH  = (size_t)Bsz * Hsz;         // 0.5M

  char* p = (char*)d_ws;
  unsigned short* xh   = (unsigned short*)p; p += NX * 2;
  unsigned short* xl   = (unsigned short*)p; p += NX * 2;
  unsigned short* wihh = (unsigned short*)p; p += NW3 * 2;
  unsigned short* wihl = (unsigned short*)p; p += NW3 * 2;
  unsigned short* whhh = (unsigned short*)p; p += NW3 * 2;
  unsigned short* whhl = (unsigned short*)p; p += NW3 * 2;
  unsigned short* wlh  = (unsigned short*)p; p += NW1 * 2;
  unsigned short* wll  = (unsigned short*)p; p += NW1 * 2;
  float* ring = (float*)p; p += (size_t)8 * Bsz * 3072 * 4;   // 50.3 MB
  float* ghb  = (float*)p; p += (size_t)Bsz * 3072 * 4;
  float* gi0  = (float*)p; p += 3072 * 4;
  float* hf0  = (float*)p; p += NH * 4;
  float* hf1  = (float*)p; p += NH * 4;
  unsigned short* hh0 = (unsigned short*)p; p += NH * 2;
  unsigned short* hl0 = (unsigned short*)p; p += NH * 2;
  unsigned short* hh1 = (unsigned short*)p; p += NH * 2;
  unsigned short* hl1 = (unsigned short*)p; p += NH * 2;
  float* q = (float*)p; p += NH * 4;
  unsigned int* flag  = (unsigned int*)p; p += Bsz * 4;
  unsigned int* valid = (unsigned int*)p; p += Bsz * 4;

  k_split<<<(int)(NX / 4 + 255) / 256, 256, 0, stream>>>(tg, xh, xl, (int)(NX / 4));
  k_split<<<(int)(NW3 / 4 + 255) / 256, 256, 0, stream>>>(wih, wihh, wihl, (int)(NW3 / 4));
  k_split<<<(int)(NW3 / 4 + 255) / 256, 256, 0, stream>>>(whh, whhh, whhl, (int)(NW3 / 4));
  k_split<<<(int)(NW1 / 4 + 255) / 256, 256, 0, stream>>>(wlw, wlh, wll, (int)(NW1 / 4));
  k_init<<<Bsz, 256, 0, stream>>>(ih, pos, hf0, hh0, hl0, flag, valid);
  k_gemv0<<<48, 256, 0, stream>>>(S, wih, gi0);

  for (int t = 0; t < Tsz; ++t) {
    // launch GI chunk GEMMs just-in-time (8 steps per chunk)
    if (t == 1 || t == 9 || t == 17 || t == 25) {
      const int ns = (t == 25) ? 5 : 8;
      k_gemm3<1><<<dim3(48, ns * 8), 256, 0, stream>>>(xh, xl, wihh, wihl, ring, 3072, nullptr, t);
    }
    const float* hfi = (t & 1) ? hf1 : hf0;
    float*       hfo = (t & 1) ? hf0 : hf1;
    const unsigned short* hhi = (t & 1) ? hh1 : hh0;
    const unsigned short* hli = (t & 1) ? hl1 : hl0;
    unsigned short* hho = (t & 1) ? hh0 : hh1;
    unsigned short* hlo = (t & 1) ? hl0 : hl1;

    // gh = h @ W_hh^T  (plain GEMM into ghb)
    k_gemm3<0><<<dim3(48, 8), 256, 0, stream>>>(hhi, hli, whhh, whhl, ghb, 3072, nullptr, 0);
    // combine -> h_new (+ bf16 splits)
    const float* gip = (t == 0) ? gi0 : (ring + (size_t)(t & 7) * Bsz * 3072);
    k_combine<<<(Bsz * Hsz) / 256, 256, 0, stream>>>(ghb, gip, (t == 0) ? 0 : 3072,
                                                     bih, bhh, hfi, hfo, hho, hlo);
    // q = h_new @ Wl_w^T + Wl_b
    k_gemm3<0><<<dim3(16, 8), 256, 0, stream>>>(hho, hlo, wlh, wll, q, Hsz, wlb, 0);
    // attention + softmax + flag + outputs
    k_attn<<<Bsz, 256, 0, stream>>>(q, ih, flag, valid, out, t);
  }
}

// Round 5
// 2683.337 us; speedup vs baseline: 1.7311x; 1.7311x over previous
//
#include <hip/hip_runtime.h>

#define Bsz 512
#define Lsz 30
#define Hsz 1024
#define Tsz 30

typedef __bf16 bf16x8 __attribute__((ext_vector_type(8)));
typedef float  f32x4  __attribute__((ext_vector_type(4)));
typedef unsigned int u32;

__device__ __forceinline__ float bf2f(unsigned short s) {
  union { u32 u; float f; } v; v.u = ((u32)s) << 16; return v.f;
}
__device__ __forceinline__ unsigned short f2bf(float f) {
  union { float f; u32 u; } v; v.f = f;
  return (unsigned short)((v.u + 0x7FFFu + ((v.u >> 16) & 1u)) >> 16);
}
__device__ __forceinline__ bf16x8 ld8u(const unsigned short* p) {
  return *reinterpret_cast<const bf16x8*>(p);
}
// async global->LDS, 16B per lane; LDS dest = uniform base + lane*16
__device__ __forceinline__ void stage16(const unsigned short* g, unsigned short* l) {
  __builtin_amdgcn_global_load_lds(
      (const __attribute__((address_space(1))) u32*)g,
      (__attribute__((address_space(3))) u32*)l, 16, 0, 0);
}

// ---------------- split fp32 -> (hi, lo) bf16 planes ---------------------------
__global__ __launch_bounds__(256) void k_split(
    const float* __restrict__ src, unsigned short* __restrict__ hi,
    unsigned short* __restrict__ lo, int n4)
{
  const int i = blockIdx.x * 256 + threadIdx.x;
  if (i >= n4) return;
  const float4 v = ((const float4*)src)[i];
  unsigned short h0 = f2bf(v.x), h1 = f2bf(v.y), h2 = f2bf(v.z), h3 = f2bf(v.w);
  unsigned short l0 = f2bf(v.x - bf2f(h0)), l1 = f2bf(v.y - bf2f(h1));
  unsigned short l2 = f2bf(v.z - bf2f(h2)), l3 = f2bf(v.w - bf2f(h3));
  ((ushort4*)hi)[i] = make_ushort4(h0, h1, h2, h3);
  ((ushort4*)lo)[i] = make_ushort4(l0, l1, l2, l3);
}

// ---------------- init: h0 = mean_L(input_hidden) + splits, masks --------------
__global__ __launch_bounds__(256) void k_init(
    const float* __restrict__ ih, const int* __restrict__ pos,
    float* __restrict__ hf, unsigned short* __restrict__ hh,
    unsigned short* __restrict__ hl,
    unsigned int* __restrict__ flag, unsigned int* __restrict__ valid)
{
  const int b = blockIdx.x;
  const float* base = ih + (size_t)b * Lsz * Hsz;
  #pragma unroll
  for (int i = 0; i < 4; ++i) {
    const int c = threadIdx.x + 256 * i;
    float s = 0.f;
    for (int l = 0; l < Lsz; ++l) s += base[l * Hsz + c];
    s /= 30.0f;
    const size_t o = (size_t)b * Hsz + c;
    hf[o] = s;
    const unsigned short h = f2bf(s);
    hh[o] = h; hl[o] = f2bf(s - bf2f(h));
  }
  if (threadIdx.x == 0) {
    int ss = 0;
    for (int l = 0; l < Lsz; ++l) ss += (pos[b * Lsz + l] != -1) ? 1 : 0;
    valid[b] = (ss >= 32) ? 0xFFFFFFFFu : ((1u << ss) - 1u);
    flag[b]  = 0u;
  }
}

// ---------------- gi0 = S @ W_ih^T (fp32 GEMV, 3072 outputs) -------------------
__global__ __launch_bounds__(256) void k_gemv0(
    const float* __restrict__ S, const float* __restrict__ wih,
    float* __restrict__ gi0)
{
  const int n = blockIdx.x * 64 + (threadIdx.x >> 2);
  const int part = threadIdx.x & 3;
  const float4* s4 = (const float4*)S + part * 64;
  const float4* w4 = (const float4*)(wih + (size_t)n * Hsz) + part * 64;
  float s = 0.f;
  #pragma unroll 8
  for (int i = 0; i < 64; ++i) {
    const float4 a = s4[i], b = w4[i];
    s = fmaf(a.x, b.x, s); s = fmaf(a.y, b.y, s);
    s = fmaf(a.z, b.z, s); s = fmaf(a.w, b.w, s);
  }
  s += __shfl_xor(s, 1, 64);
  s += __shfl_xor(s, 2, 64);
  if (part == 0) gi0[n] = s;
}

// ============ tiled 3-pass split-bf16 GEMM with fragment-packed LDS ============
// LDS layout per plane: [rowgroup g][lane][8 bf16] -> ds_read_b128 conflict-free.
// MODE 0: C[row*ldc + c] = acc + bias[c].   MODE 1 (GI): A-row remap into tgt,
// C written into 8-slot ring [slot][512][3072].
template<int BM, int BN, int MODE>
__global__ __launch_bounds__(256) void k_tgemm(
    const unsigned short* __restrict__ Ah, const unsigned short* __restrict__ Al,
    const unsigned short* __restrict__ Bh, const unsigned short* __restrict__ Bl,
    float* __restrict__ C, int ldc, const float* __restrict__ bias, int t0)
{
  constexpr int MF = BM / 32;          // frags per wave (M)
  constexpr int NF = BN / 32;          // frags per wave (N)
  constexpr int ACH = BM / 16;         // chunks per A plane
  constexpr int BCH = BN / 16;
  constexpr int CPW = (2 * (ACH + BCH)) / 4;
  constexpr int oAh = 0, oAl = BM * 32, oBh = 2 * BM * 32, oBl = 2 * BM * 32 + BN * 32;

  __shared__ unsigned short lds[2 * (BM + BN) * 32];

  const int w = threadIdx.x >> 6, lane = threadIdx.x & 63;
  const int wm = w >> 1, wn = w & 1;
  const int lr = lane & 15, lg = lane >> 4;
  const int bm = blockIdx.y * BM, bn = blockIdx.x * BN;

  const unsigned short* gp[CPW];
  int ldso[CPW];
  #pragma unroll
  for (int i = 0; i < CPW; ++i) {
    const int cid = w * CPW + i;
    const unsigned short* base; long row; int off;
    if (cid < ACH)              { const int g = cid;             row = bm + g * 16 + lr; base = Ah; off = oAh + g * 512; }
    else if (cid < 2 * ACH)     { const int g = cid - ACH;       row = bm + g * 16 + lr; base = Al; off = oAl + g * 512; }
    else if (cid < 2 * ACH + BCH){ const int g = cid - 2 * ACH;  row = bn + g * 16 + lr; base = Bh; off = oBh + g * 512; }
    else                        { const int g = cid - 2 * ACH - BCH; row = bn + g * 16 + lr; base = Bl; off = oBl + g * 512; }
    if (MODE == 1 && cid < 2 * ACH)
      row = (long)((int)row & 511) * Tsz + (t0 - 1) + ((int)row >> 9);
    gp[i] = base + row * Hsz + lg * 8;
    ldso[i] = off;
  }

  f32x4 acc[MF][NF] = {};

  for (int ks = 0; ks < 32; ++ks) {
    #pragma unroll
    for (int i = 0; i < CPW; ++i) { stage16(gp[i], &lds[ldso[i]]); gp[i] += 32; }
    __syncthreads();
    bf16x8 a_h[MF], a_l[MF], b_h[NF], b_l[NF];
    #pragma unroll
    for (int m = 0; m < MF; ++m) {
      const int g = wm * (ACH / 2) + m;
      a_h[m] = ld8u(&lds[oAh + g * 512 + lane * 8]);
      a_l[m] = ld8u(&lds[oAl + g * 512 + lane * 8]);
    }
    #pragma unroll
    for (int n = 0; n < NF; ++n) {
      const int g = wn * (BCH / 2) + n;
      b_h[n] = ld8u(&lds[oBh + g * 512 + lane * 8]);
      b_l[n] = ld8u(&lds[oBl + g * 512 + lane * 8]);
    }
    #pragma unroll
    for (int m = 0; m < MF; ++m)
      #pragma unroll
      for (int n = 0; n < NF; ++n) {
        acc[m][n] = __builtin_amdgcn_mfma_f32_16x16x32_bf16(a_h[m], b_h[n], acc[m][n], 0, 0, 0);
        acc[m][n] = __builtin_amdgcn_mfma_f32_16x16x32_bf16(a_h[m], b_l[n], acc[m][n], 0, 0, 0);
        acc[m][n] = __builtin_amdgcn_mfma_f32_16x16x32_bf16(a_l[m], b_h[n], acc[m][n], 0, 0, 0);
      }
    __syncthreads();
  }

  #pragma unroll
  for (int n = 0; n < NF; ++n) {
    const int c = bn + wn * (BN / 2) + n * 16 + lr;
    const float bb = (MODE == 0 && bias) ? bias[c] : 0.f;
    #pragma unroll
    for (int m = 0; m < MF; ++m) {
      #pragma unroll
      for (int rr = 0; rr < 4; ++rr) {
        const int row = bm + wm * (BM / 2) + m * 16 + lg * 4 + rr;
        if (MODE == 1) {
          const int slot = (t0 + (row >> 9)) & 7;
          C[((size_t)slot * Bsz + (row & 511)) * 3072 + c] = acc[m][n][rr];
        } else {
          C[(size_t)row * ldc + c] = acc[m][n][rr] + bb;
        }
      }
    }
  }
}

// ============ fused gh-GEMM (3 gates) + GRU combine ============================
// BM=64 batch rows, 32 h-cols, 3 gates. grid (32,8) = 256 blocks.
__global__ __launch_bounds__(256) void k_ghc(
    const unsigned short* __restrict__ Hh, const unsigned short* __restrict__ Hl,
    const unsigned short* __restrict__ Wh, const unsigned short* __restrict__ Wl,
    const float* __restrict__ gi, int gi_rs,
    const float* __restrict__ bih, const float* __restrict__ bhh,
    const float* __restrict__ hf_in, float* __restrict__ hf_out,
    unsigned short* __restrict__ hh, unsigned short* __restrict__ hl)
{
  // LDS planes (elements): Ah 2048, Al 2048, Bh 3072 (3 gates x 2 colgroups), Bl 3072
  constexpr int oAh = 0, oAl = 2048, oBh = 4096, oBl = 7168;
  __shared__ unsigned short lds[10240];

  const int w = threadIdx.x >> 6, lane = threadIdx.x & 63;
  const int wm = w >> 1, wn = w & 1;
  const int lr = lane & 15, lg = lane >> 4;
  const int bm = blockIdx.y * 64, bn = blockIdx.x * 32;

  const unsigned short* gp[5];
  int ldso[5];
  #pragma unroll
  for (int i = 0; i < 5; ++i) {
    const int cid = w + 4 * i;   // 0..19
    const unsigned short* base; long row; int off;
    if (cid < 4)        { const int g = cid;      row = bm + g * 16 + lr;                      base = Hh; off = oAh + g * 512; }
    else if (cid < 8)   { const int g = cid - 4;  row = bm + g * 16 + lr;                      base = Hl; off = oAl + g * 512; }
    else if (cid < 14)  { const int g = cid - 8;  row = (g >> 1) * 1024 + bn + (g & 1) * 16 + lr; base = Wh; off = oBh + g * 512; }
    else                { const int g = cid - 14; row = (g >> 1) * 1024 + bn + (g & 1) * 16 + lr; base = Wl; off = oBl + g * 512; }
    gp[i] = base + row * Hsz + lg * 8;
    ldso[i] = off;
  }

  f32x4 acc[3][2] = {};   // [gate][mf]

  for (int ks = 0; ks < 32; ++ks) {
    #pragma unroll
    for (int i = 0; i < 5; ++i) { stage16(gp[i], &lds[ldso[i]]); gp[i] += 32; }
    __syncthreads();
    bf16x8 ah[2], al[2], bh[3], bl[3];
    #pragma unroll
    for (int m = 0; m < 2; ++m) {
      const int g = wm * 2 + m;
      ah[m] = ld8u(&lds[oAh + g * 512 + lane * 8]);
      al[m] = ld8u(&lds[oAl + g * 512 + lane * 8]);
    }
    #pragma unroll
    for (int gt = 0; gt < 3; ++gt) {
      const int g = gt * 2 + wn;
      bh[gt] = ld8u(&lds[oBh + g * 512 + lane * 8]);
      bl[gt] = ld8u(&lds[oBl + g * 512 + lane * 8]);
    }
    #pragma unroll
    for (int gt = 0; gt < 3; ++gt)
      #pragma unroll
      for (int m = 0; m < 2; ++m) {
        acc[gt][m] = __builtin_amdgcn_mfma_f32_16x16x32_bf16(ah[m], bh[gt], acc[gt][m], 0, 0, 0);
        acc[gt][m] = __builtin_amdgcn_mfma_f32_16x16x32_bf16(ah[m], bl[gt], acc[gt][m], 0, 0, 0);
        acc[gt][m] = __builtin_amdgcn_mfma_f32_16x16x32_bf16(al[m], bh[gt], acc[gt][m], 0, 0, 0);
      }
    __syncthreads();
  }

  const int c = bn + wn * 16 + lr;
  const float b_ir = bih[c], b_iz = bih[1024 + c], b_in = bih[2048 + c];
  const float b_hr = bhh[c], b_hz = bhh[1024 + c], b_hn = bhh[2048 + c];
  #pragma unroll
  for (int m = 0; m < 2; ++m) {
    #pragma unroll
    for (int rr = 0; rr < 4; ++rr) {
      const int row = bm + wm * 32 + m * 16 + lg * 4 + rr;
      const size_t gr = (size_t)row * gi_rs;
      const float pr = gi[gr + c]        + b_ir + acc[0][m][rr] + b_hr;
      const float pz = gi[gr + 1024 + c] + b_iz + acc[1][m][rr] + b_hz;
      const float r = 1.f / (1.f + expf(-pr));
      const float z = 1.f / (1.f + expf(-pz));
      const float n = tanhf(gi[gr + 2048 + c] + b_in + r * (acc[2][m][rr] + b_hn));
      const size_t o = (size_t)row * Hsz + c;
      const float h = (1.f - z) * n + z * hf_in[o];
      hf_out[o] = h;
      const unsigned short hb = f2bf(h);
      hh[o] = hb; hl[o] = f2bf(h - bf2f(hb));
    }
  }
}

// ---------------- attention scores + masked softmax + argmax/flag + outputs ----
__global__ __launch_bounds__(256) void k_attn(
    const float* __restrict__ q, const float* __restrict__ ih,
    unsigned int* __restrict__ flag, const unsigned int* __restrict__ valid,
    float* __restrict__ out, int t)
{
  const int b = blockIdx.x;
  __shared__ float pre_s[32];
  __shared__ float top_s[32];
  const int w = threadIdx.x >> 6;
  const int lane = threadIdx.x & 63;

  float qr[16];
  const float4* q4 = (const float4*)(q + (size_t)b * Hsz);
  #pragma unroll
  for (int i = 0; i < 4; ++i) {
    const float4 v = q4[lane * 4 + i];
    qr[4*i+0] = v.x; qr[4*i+1] = v.y; qr[4*i+2] = v.z; qr[4*i+3] = v.w;
  }

  for (int l = w; l < Lsz; l += 4) {
    const float4* r4 = (const float4*)(ih + (size_t)b * Lsz * Hsz + (size_t)l * Hsz);
    float s = 0.f;
    #pragma unroll
    for (int i = 0; i < 4; ++i) {
      const float4 v = r4[lane * 4 + i];
      s = fmaf(qr[4*i+0], v.x, s);
      s = fmaf(qr[4*i+1], v.y, s);
      s = fmaf(qr[4*i+2], v.z, s);
      s = fmaf(qr[4*i+3], v.w, s);
    }
    #pragma unroll
    for (int off = 32; off >= 1; off >>= 1) s += __shfl_xor(s, off, 64);
    if (lane == 0) pre_s[l] = s;
  }
  __syncthreads();

  if (threadIdx.x == 0) {
    const unsigned int fl = flag[b];
    const unsigned int ex = fl | ~valid[b];
    float best = -3.4e38f; int am = 0;
    for (int l = 0; l < Lsz; ++l) {
      if (!((ex >> l) & 1u)) { const float v = pre_s[l]; if (v > best) { best = v; am = l; } }
    }
    float sum = 0.f;
    for (int l = 0; l < Lsz; ++l) {
      const float e = ((ex >> l) & 1u) ? 0.f : expf(pre_s[l] - best);
      top_s[l] = e; sum += e;
    }
    const float inv = 1.f / sum;
    for (int l = 0; l < Lsz; ++l) top_s[l] *= inv;
    flag[b] = fl | (1u << am);
  }
  __syncthreads();

  if (threadIdx.x < Lsz) {
    const int l = threadIdx.x;
    out[(size_t)b * (Tsz * Lsz) + t * Lsz + l] = pre_s[l];
    out[(size_t)Bsz * Tsz * Lsz + (size_t)b * (Tsz * Lsz) + t * Lsz + l] = top_s[l];
  }
}

extern "C" void kernel_launch(void* const* d_in, const int* in_sizes, int n_in,
                              void* d_out, int out_size, void* d_ws, size_t ws_size,
                              hipStream_t stream) {
  const float* ih  = (const float*)d_in[0];
  const float* tg  = (const float*)d_in[1];
  const int*   pos = (const int*)d_in[2];
  const float* S   = (const float*)d_in[4];
  const float* wih = (const float*)d_in[5];
  const float* whh = (const float*)d_in[6];
  const float* bih = (const float*)d_in[7];
  const float* bhh = (const float*)d_in[8];
  const float* wlw = (const float*)d_in[9];
  const float* wlb = (const float*)d_in[10];
  float* out = (float*)d_out;

  const size_t NX  = (size_t)Bsz * Tsz * Hsz;
  const size_t NW3 = (size_t)3 * Hsz * Hsz;
  const size_t NW1 = (size_t)Hsz * Hsz;
  const size_t NH  = (size_t)Bsz * Hsz;

  char* p = (char*)d_ws;
  unsigned short* xh   = (unsigned short*)p; p += NX * 2;
  unsigned short* xl   = (unsigned short*)p; p += NX * 2;
  unsigned short* wihh = (unsigned short*)p; p += NW3 * 2;
  unsigned short* wihl = (unsigned short*)p; p += NW3 * 2;
  unsigned short* whhh = (unsigned short*)p; p += NW3 * 2;
  unsigned short* whhl = (unsigned short*)p; p += NW3 * 2;
  unsigned short* wlh  = (unsigned short*)p; p += NW1 * 2;
  unsigned short* wll  = (unsigned short*)p; p += NW1 * 2;
  float* ring = (float*)p; p += (size_t)8 * Bsz * 3072 * 4;
  float* gi0  = (float*)p; p += 3072 * 4;
  float* hf0  = (float*)p; p += NH * 4;
  float* hf1  = (float*)p; p += NH * 4;
  unsigned short* hh0 = (unsigned short*)p; p += NH * 2;
  unsigned short* hl0 = (unsigned short*)p; p += NH * 2;
  unsigned short* hh1 = (unsigned short*)p; p += NH * 2;
  unsigned short* hl1 = (unsigned short*)p; p += NH * 2;
  float* q = (float*)p; p += NH * 4;
  unsigned int* flag  = (unsigned int*)p; p += Bsz * 4;
  unsigned int* valid = (unsigned int*)p; p += Bsz * 4;

  k_split<<<(int)(NX / 4 + 255) / 256, 256, 0, stream>>>(tg, xh, xl, (int)(NX / 4));
  k_split<<<(int)(NW3 / 4 + 255) / 256, 256, 0, stream>>>(wih, wihh, wihl, (int)(NW3 / 4));
  k_split<<<(int)(NW3 / 4 + 255) / 256, 256, 0, stream>>>(whh, whhh, whhl, (int)(NW3 / 4));
  k_split<<<(int)(NW1 / 4 + 255) / 256, 256, 0, stream>>>(wlw, wlh, wll, (int)(NW1 / 4));
  k_init<<<Bsz, 256, 0, stream>>>(ih, pos, hf0, hh0, hl0, flag, valid);
  k_gemv0<<<48, 256, 0, stream>>>(S, wih, gi0);

  for (int t = 0; t < Tsz; ++t) {
    if (t == 1 || t == 9 || t == 17 || t == 25) {
      const int ns = (t == 25) ? 5 : 8;
      k_tgemm<128, 128, 1><<<dim3(24, ns * 4), 256, 0, stream>>>(
          xh, xl, wihh, wihl, ring, 3072, nullptr, t);
    }
    const float* hfi = (t & 1) ? hf1 : hf0;
    float*       hfo = (t & 1) ? hf0 : hf1;
    const unsigned short* hhi = (t & 1) ? hh1 : hh0;
    const unsigned short* hli = (t & 1) ? hl1 : hl0;
    unsigned short* hho = (t & 1) ? hh0 : hh1;
    unsigned short* hlo = (t & 1) ? hl0 : hl1;

    const float* gip = (t == 0) ? gi0 : (ring + (size_t)(t & 7) * Bsz * 3072);
    k_ghc<<<dim3(32, 8), 256, 0, stream>>>(hhi, hli, whhh, whhl, gip, (t == 0) ? 0 : 3072,
                                           bih, bhh, hfi, hfo, hho, hlo);
    k_tgemm<64, 32, 0><<<dim3(32, 8), 256, 0, stream>>>(hho, hlo, wlh, wll, q, Hsz, wlb, 0);
    k_attn<<<Bsz, 256, 0, stream>>>(q, ih, flag, valid, out, t);
  }
}

// Round 7
// 2330.215 us; speedup vs baseline: 1.9934x; 1.1515x over previous
//
#include <hip/hip_runtime.h>

#define Bsz 512
#define Lsz 30
#define Hsz 1024
#define Tsz 30

typedef __bf16 bf16x8 __attribute__((ext_vector_type(8)));
typedef unsigned short u16x8 __attribute__((ext_vector_type(8)));
typedef float  f32x4  __attribute__((ext_vector_type(4)));
typedef unsigned int u32;

__device__ __forceinline__ float bf2f(unsigned short s) {
  union { u32 u; float f; } v; v.u = ((u32)s) << 16; return v.f;
}
__device__ __forceinline__ unsigned short f2bf(float f) {
  union { float f; u32 u; } v; v.f = f;
  return (unsigned short)((v.u + 0x7FFFu + ((v.u >> 16) & 1u)) >> 16);
}
__device__ __forceinline__ bf16x8 ld8u(const unsigned short* p) {
  return *reinterpret_cast<const bf16x8*>(p);
}
__device__ __forceinline__ void stage16(const unsigned short* g, unsigned short* l) {
  __builtin_amdgcn_global_load_lds(
      (const __attribute__((address_space(1))) u32*)g,
      (__attribute__((address_space(3))) u32*)l, 16, 0, 0);
}

// ---------------- split fp32 -> (hi, lo) bf16 planes (weights, one-time) -------
__global__ __launch_bounds__(256) void k_split(
    const float* __restrict__ src, unsigned short* __restrict__ hi,
    unsigned short* __restrict__ lo, int n4)
{
  const int i = blockIdx.x * 256 + threadIdx.x;
  if (i >= n4) return;
  const float4 v = ((const float4*)src)[i];
  unsigned short h0 = f2bf(v.x), h1 = f2bf(v.y), h2 = f2bf(v.z), h3 = f2bf(v.w);
  unsigned short l0 = f2bf(v.x - bf2f(h0)), l1 = f2bf(v.y - bf2f(h1));
  unsigned short l2 = f2bf(v.z - bf2f(h2)), l3 = f2bf(v.w - bf2f(h3));
  ((ushort4*)hi)[i] = make_ushort4(h0, h1, h2, h3);
  ((ushort4*)lo)[i] = make_ushort4(l0, l1, l2, l3);
}

// -------- transpose + 3-plane split: out[k][n] = in[n][k] (for Wl) -------------
__global__ __launch_bounds__(256) void k_splitT3(
    const float* __restrict__ src, unsigned short* __restrict__ t0,
    unsigned short* __restrict__ t1, unsigned short* __restrict__ t2)
{
  __shared__ float t[32][33];
  const int tid = threadIdx.x;
  const int bi = blockIdx.x * 32, bj = blockIdx.y * 32;
  const int r = tid >> 3, c4 = (tid & 7) * 4;
  const float4 v = *(const float4*)(src + (size_t)(bi + r) * Hsz + bj + c4);
  t[r][c4] = v.x; t[r][c4 + 1] = v.y; t[r][c4 + 2] = v.z; t[r][c4 + 3] = v.w;
  __syncthreads();
  ushort4 p0, p1, p2;
  float f[4] = { t[c4][r], t[c4 + 1][r], t[c4 + 2][r], t[c4 + 3][r] };
  unsigned short h[4], m[4], l[4];
  #pragma unroll
  for (int i = 0; i < 4; ++i) {
    h[i] = f2bf(f[i]);
    const float r1 = f[i] - bf2f(h[i]);
    m[i] = f2bf(r1);
    l[i] = f2bf(r1 - bf2f(m[i]));
  }
  p0 = make_ushort4(h[0], h[1], h[2], h[3]);
  p1 = make_ushort4(m[0], m[1], m[2], m[3]);
  p2 = make_ushort4(l[0], l[1], l[2], l[3]);
  const size_t o = (size_t)(bj + r) * Hsz + bi + c4;
  *(ushort4*)(t0 + o) = p0;
  *(ushort4*)(t1 + o) = p1;
  *(ushort4*)(t2 + o) = p2;
}

// ---------------- init: h0 = mean_L(ih), h splits, c0 = Wl_b . ih, masks -------
__global__ __launch_bounds__(256) void k_init(
    const float* __restrict__ ih, const int* __restrict__ pos,
    const float* __restrict__ wlb,
    float* __restrict__ hf, unsigned short* __restrict__ hh,
    unsigned short* __restrict__ hl, float* __restrict__ c0,
    unsigned int* __restrict__ flag, unsigned int* __restrict__ valid)
{
  __shared__ float red[4];
  const int b = blockIdx.x, tid = threadIdx.x;
  const int lane = tid & 63, wid = tid >> 6;
  const float4 wb = ((const float4*)wlb)[tid];
  float s0 = 0.f, s1 = 0.f, s2 = 0.f, s3 = 0.f;
  for (int l = 0; l < Lsz; ++l) {
    const float4 v = ((const float4*)(ih + ((size_t)b * Lsz + l) * Hsz))[tid];
    s0 += v.x; s1 += v.y; s2 += v.z; s3 += v.w;
    float part = v.x * wb.x + v.y * wb.y + v.z * wb.z + v.w * wb.w;
    #pragma unroll
    for (int off = 32; off >= 1; off >>= 1) part += __shfl_xor(part, off, 64);
    if (lane == 0) red[wid] = part;
    __syncthreads();
    if (tid == 0) c0[b * Lsz + l] = red[0] + red[1] + red[2] + red[3];
    __syncthreads();
  }
  const size_t o = (size_t)b * Hsz + tid * 4;
  float m[4] = { s0 / 30.f, s1 / 30.f, s2 / 30.f, s3 / 30.f };
  float4 mf = { m[0], m[1], m[2], m[3] };
  *(float4*)(hf + o) = mf;
  ushort4 h4, l4;
  h4.x = f2bf(m[0]); h4.y = f2bf(m[1]); h4.z = f2bf(m[2]); h4.w = f2bf(m[3]);
  l4.x = f2bf(m[0] - bf2f(h4.x)); l4.y = f2bf(m[1] - bf2f(h4.y));
  l4.z = f2bf(m[2] - bf2f(h4.z)); l4.w = f2bf(m[3] - bf2f(h4.w));
  *(ushort4*)(hh + o) = h4;
  *(ushort4*)(hl + o) = l4;
  if (tid == 0) {
    int ss = 0;
    for (int l = 0; l < Lsz; ++l) ss += (pos[b * Lsz + l] != -1) ? 1 : 0;
    valid[b] = (ss >= 32) ? 0xFFFFFFFFu : ((1u << ss) - 1u);
    flag[b]  = 0u;
  }
}

// ---------------- gi0 = S @ W_ih^T (fp32 GEMV, 3072 outputs) -------------------
__global__ __launch_bounds__(256) void k_gemv0(
    const float* __restrict__ S, const float* __restrict__ wih,
    float* __restrict__ gi0)
{
  const int n = blockIdx.x * 64 + (threadIdx.x >> 2);
  const int part = threadIdx.x & 3;
  const float4* s4 = (const float4*)S + part * 64;
  const float4* w4 = (const float4*)(wih + (size_t)n * Hsz) + part * 64;
  float s = 0.f;
  #pragma unroll 8
  for (int i = 0; i < 64; ++i) {
    const float4 a = s4[i], b = w4[i];
    s = fmaf(a.x, b.x, s); s = fmaf(a.y, b.y, s);
    s = fmaf(a.z, b.z, s); s = fmaf(a.w, b.w, s);
  }
  s += __shfl_xor(s, 1, 64);
  s += __shfl_xor(s, 2, 64);
  if (part == 0) gi0[n] = s;
}

// ============ GI chunk GEMM: 3-pass, A from fp32 (ROUNDED reg split), dbuf =====
// 128x128 tile, BK=32, 256 thr. A-row remap into tgt, C into 8-slot ring.
__global__ __launch_bounds__(256) void k_tgemm(
    const float* __restrict__ Afp,
    const unsigned short* __restrict__ Bh, const unsigned short* __restrict__ Bl,
    float* __restrict__ C, int t0)
{
  constexpr int oAh = 0, oAl = 4096, oBh = 8192, oBl = 12288;
  __shared__ unsigned short lds[2][16384];

  const int tid = threadIdx.x;
  const int w = tid >> 6, lane = tid & 63;
  const int wm = w >> 1, wn = w & 1;
  const int lr = lane & 15, lg = lane >> 4;
  const int bm = blockIdx.y * 128, bn = blockIdx.x * 128;

  const int ar = tid & 127, kh = tid >> 7;
  const long arow = (long)((bm + ar) & 511) * Tsz + (t0 - 1) + ((bm + ar) >> 9);
  const float* aptr = Afp + arow * Hsz + kh * 16;
  const int awo0 = (ar >> 4) * 512 + ((ar & 15) + 32 * kh) * 8;

  const unsigned short* gpB[4]; int bwo[4];
  #pragma unroll
  for (int i = 0; i < 4; ++i) {
    const int cid = (w << 2) | i;
    const unsigned short* base; int g, off;
    if (cid < 8) { base = Bh; g = cid;     off = oBh + g * 512; }
    else         { base = Bl; g = cid - 8; off = oBl + g * 512; }
    gpB[i] = base + (size_t)(bn + g * 16 + lr) * Hsz + lg * 8;
    bwo[i] = off;
  }

  float4 areg[4];
  #define LOAD_A() { _Pragma("unroll") for (int i = 0; i < 4; ++i) areg[i] = ((const float4*)aptr)[i]; aptr += 32; }
  #define STAGE_B(buf) { _Pragma("unroll") for (int i = 0; i < 4; ++i) { stage16(gpB[i], &lds[buf][bwo[i]]); gpB[i] += 32; } }
  #define WRITE_A(buf) { \
    u16x8 h0v, h1v, l0v, l1v; \
    _Pragma("unroll") for (int i = 0; i < 4; ++i) { \
      const float f[4] = { areg[i].x, areg[i].y, areg[i].z, areg[i].w }; \
      _Pragma("unroll") for (int c = 0; c < 4; ++c) { \
        const int j = 4 * i + c; \
        const unsigned short hb = f2bf(f[c]); \
        const unsigned short lb = f2bf(f[c] - bf2f(hb)); \
        if (j < 8) { h0v[j] = hb; l0v[j] = lb; } else { h1v[j - 8] = hb; l1v[j - 8] = lb; } \
      } \
    } \
    *(u16x8*)&lds[buf][oAh + awo0]       = h0v; \
    *(u16x8*)&lds[buf][oAh + awo0 + 128] = h1v; \
    *(u16x8*)&lds[buf][oAl + awo0]       = l0v; \
    *(u16x8*)&lds[buf][oAl + awo0 + 128] = l1v; }

  f32x4 acc[4][4] = {};

  LOAD_A();
  STAGE_B(0);
  WRITE_A(0);
  __syncthreads();

  for (int ks = 0; ks < 32; ++ks) {
    const int cur = ks & 1;
    if (ks < 31) { STAGE_B(cur ^ 1); LOAD_A(); }
    {
      const unsigned short* L = &lds[cur][0];
      bf16x8 a_h[4], a_l[4], b_h[4], b_l[4];
      #pragma unroll
      for (int m = 0; m < 4; ++m) {
        const int g = wm * 4 + m;
        a_h[m] = ld8u(L + oAh + g * 512 + lane * 8);
        a_l[m] = ld8u(L + oAl + g * 512 + lane * 8);
      }
      #pragma unroll
      for (int n = 0; n < 4; ++n) {
        const int g = wn * 4 + n;
        b_h[n] = ld8u(L + oBh + g * 512 + lane * 8);
        b_l[n] = ld8u(L + oBl + g * 512 + lane * 8);
      }
      #pragma unroll
      for (int m = 0; m < 4; ++m)
        #pragma unroll
        for (int n = 0; n < 4; ++n) {
          acc[m][n] = __builtin_amdgcn_mfma_f32_16x16x32_bf16(a_h[m], b_h[n], acc[m][n], 0, 0, 0);
          acc[m][n] = __builtin_amdgcn_mfma_f32_16x16x32_bf16(a_h[m], b_l[n], acc[m][n], 0, 0, 0);
          acc[m][n] = __builtin_amdgcn_mfma_f32_16x16x32_bf16(a_l[m], b_h[n], acc[m][n], 0, 0, 0);
        }
    }
    __syncthreads();
    if (ks < 31) { WRITE_A(cur ^ 1); __syncthreads(); }
  }

  #pragma unroll
  for (int n = 0; n < 4; ++n) {
    const int col = bn + wn * 64 + n * 16 + lr;
    #pragma unroll
    for (int m = 0; m < 4; ++m) {
      #pragma unroll
      for (int rr = 0; rr < 4; ++rr) {
        const int row = bm + wm * 64 + m * 16 + lg * 4 + rr;
        const int slot = (t0 + (row >> 9)) & 7;
        C[((size_t)slot * Bsz + (row & 511)) * 3072 + col] = acc[m][n][rr];
      }
    }
  }
  #undef LOAD_A
  #undef STAGE_B
  #undef WRITE_A
}

// ============ G = ih @ WlT : 3-plane split, 6-pass (fp32-grade) ================
// 64x64 tile, BK=32, 256 thr (4 waves 2x2), single-buffer 2-barrier loop.
__global__ __launch_bounds__(256) void k_gemmG(
    const float* __restrict__ Afp,
    const unsigned short* __restrict__ B0, const unsigned short* __restrict__ B1,
    const unsigned short* __restrict__ B2, float* __restrict__ C)
{
  // A planes: p*2048; B planes: 6144 + p*2048  (u16 elements)
  __shared__ unsigned short lds[12288];

  const int tid = threadIdx.x;
  const int w = tid >> 6, lane = tid & 63;
  const int wm = w >> 1, wn = w & 1;
  const int lr = lane & 15, lg = lane >> 4;
  const int bm = blockIdx.y * 64, bn = blockIdx.x * 64;

  const int ar = tid & 63, kh = tid >> 6;            // row, k-octet (8 k's)
  const float* aptr = Afp + (size_t)(bm + ar) * Hsz + kh * 8;
  const int awo = (ar >> 4) * 512 + ((ar & 15) + 16 * kh) * 8;

  const unsigned short* gpB[3]; int bwo[3];
  #pragma unroll
  for (int i = 0; i < 3; ++i) {
    const int cid = w * 3 + i;                       // 0..11
    const int p = cid >> 2, g = cid & 3;
    const unsigned short* base = (p == 0) ? B0 : (p == 1) ? B1 : B2;
    gpB[i] = base + (size_t)(bn + g * 16 + lr) * Hsz + lg * 8;
    bwo[i] = 6144 + p * 2048 + g * 512;
  }

  f32x4 acc[2][2] = {};

  for (int ks = 0; ks < 32; ++ks) {
    // A: 8 floats -> 3 planes
    const float4 va = ((const float4*)aptr)[0];
    const float4 vb = ((const float4*)aptr)[1];
    aptr += 32;
    u16x8 p0, p1, p2;
    {
      const float f[8] = { va.x, va.y, va.z, va.w, vb.x, vb.y, vb.z, vb.w };
      #pragma unroll
      for (int j = 0; j < 8; ++j) {
        const unsigned short h = f2bf(f[j]);
        const float r1 = f[j] - bf2f(h);
        const unsigned short m_ = f2bf(r1);
        const unsigned short l_ = f2bf(r1 - bf2f(m_));
        p0[j] = h; p1[j] = m_; p2[j] = l_;
      }
    }
    #pragma unroll
    for (int i = 0; i < 3; ++i) { stage16(gpB[i], &lds[bwo[i]]); gpB[i] += 32; }
    *(u16x8*)&lds[awo]        = p0;
    *(u16x8*)&lds[2048 + awo] = p1;
    *(u16x8*)&lds[4096 + awo] = p2;
    __syncthreads();

    bf16x8 ap[3][2], bp[3][2];
    #pragma unroll
    for (int p = 0; p < 3; ++p)
      #pragma unroll
      for (int m = 0; m < 2; ++m) {
        ap[p][m] = ld8u(&lds[p * 2048 + (wm * 2 + m) * 512 + lane * 8]);
        bp[p][m] = ld8u(&lds[6144 + p * 2048 + (wn * 2 + m) * 512 + lane * 8]);
      }
    #pragma unroll
    for (int m = 0; m < 2; ++m)
      #pragma unroll
      for (int n = 0; n < 2; ++n) {
        acc[m][n] = __builtin_amdgcn_mfma_f32_16x16x32_bf16(ap[0][m], bp[0][n], acc[m][n], 0, 0, 0);
        acc[m][n] = __builtin_amdgcn_mfma_f32_16x16x32_bf16(ap[0][m], bp[1][n], acc[m][n], 0, 0, 0);
        acc[m][n] = __builtin_amdgcn_mfma_f32_16x16x32_bf16(ap[1][m], bp[0][n], acc[m][n], 0, 0, 0);
        acc[m][n] = __builtin_amdgcn_mfma_f32_16x16x32_bf16(ap[0][m], bp[2][n], acc[m][n], 0, 0, 0);
        acc[m][n] = __builtin_amdgcn_mfma_f32_16x16x32_bf16(ap[1][m], bp[1][n], acc[m][n], 0, 0, 0);
        acc[m][n] = __builtin_amdgcn_mfma_f32_16x16x32_bf16(ap[2][m], bp[0][n], acc[m][n], 0, 0, 0);
      }
    __syncthreads();
  }

  #pragma unroll
  for (int n = 0; n < 2; ++n) {
    const int col = bn + wn * 32 + n * 16 + lr;
    #pragma unroll
    for (int m = 0; m < 2; ++m) {
      #pragma unroll
      for (int rr = 0; rr < 4; ++rr) {
        const int row = bm + wm * 32 + m * 16 + lg * 4 + rr;
        C[(size_t)row * Hsz + col] = acc[m][n][rr];
      }
    }
  }
}

// ============ fused gh-GEMM (3 gates) + GRU combine, double-buffered ===========
__global__ __launch_bounds__(256) void k_ghc(
    const unsigned short* __restrict__ Hh, const unsigned short* __restrict__ Hl,
    const unsigned short* __restrict__ Wh, const unsigned short* __restrict__ Wl,
    const float* __restrict__ gi, int gi_rs,
    const float* __restrict__ bih, const float* __restrict__ bhh,
    const float* __restrict__ hf_in, float* __restrict__ hf_out,
    unsigned short* __restrict__ hh, unsigned short* __restrict__ hl)
{
  constexpr int oAh = 0, oAl = 2048, oBh = 4096, oBl = 7168;
  __shared__ unsigned short lds[2][10240];

  const int w = threadIdx.x >> 6, lane = threadIdx.x & 63;
  const int wm = w >> 1, wn = w & 1;
  const int lr = lane & 15, lg = lane >> 4;
  const int bm = blockIdx.y * 64, bn = blockIdx.x * 32;

  const unsigned short* gp[5];
  int ldso[5];
  #pragma unroll
  for (int i = 0; i < 5; ++i) {
    const int cid = w + 4 * i;   // 0..19
    const unsigned short* base; long row; int off;
    if (cid < 4)       { const int g = cid;      row = bm + g * 16 + lr;                          base = Hh; off = oAh + g * 512; }
    else if (cid < 8)  { const int g = cid - 4;  row = bm + g * 16 + lr;                          base = Hl; off = oAl + g * 512; }
    else if (cid < 14) { const int g = cid - 8;  row = (g >> 1) * 1024 + bn + (g & 1) * 16 + lr;  base = Wh; off = oBh + g * 512; }
    else               { const int g = cid - 14; row = (g >> 1) * 1024 + bn + (g & 1) * 16 + lr;  base = Wl; off = oBl + g * 512; }
    gp[i] = base + row * Hsz + lg * 8;
    ldso[i] = off;
  }

  f32x4 acc[3][2] = {};

  #pragma unroll
  for (int i = 0; i < 5; ++i) { stage16(gp[i], &lds[0][ldso[i]]); gp[i] += 32; }
  __syncthreads();

  for (int ks = 0; ks < 32; ++ks) {
    const int cur = ks & 1;
    if (ks < 31) {
      #pragma unroll
      for (int i = 0; i < 5; ++i) { stage16(gp[i], &lds[cur ^ 1][ldso[i]]); gp[i] += 32; }
    }
    const unsigned short* L = &lds[cur][0];
    bf16x8 ah[2], al[2], bh[3], bl[3];
    #pragma unroll
    for (int m = 0; m < 2; ++m) {
      const int g = wm * 2 + m;
      ah[m] = ld8u(L + oAh + g * 512 + lane * 8);
      al[m] = ld8u(L + oAl + g * 512 + lane * 8);
    }
    #pragma unroll
    for (int gt = 0; gt < 3; ++gt) {
      const int g = gt * 2 + wn;
      bh[gt] = ld8u(L + oBh + g * 512 + lane * 8);
      bl[gt] = ld8u(L + oBl + g * 512 + lane * 8);
    }
    #pragma unroll
    for (int gt = 0; gt < 3; ++gt)
      #pragma unroll
      for (int m = 0; m < 2; ++m) {
        acc[gt][m] = __builtin_amdgcn_mfma_f32_16x16x32_bf16(ah[m], bh[gt], acc[gt][m], 0, 0, 0);
        acc[gt][m] = __builtin_amdgcn_mfma_f32_16x16x32_bf16(ah[m], bl[gt], acc[gt][m], 0, 0, 0);
        acc[gt][m] = __builtin_amdgcn_mfma_f32_16x16x32_bf16(al[m], bh[gt], acc[gt][m], 0, 0, 0);
      }
    __syncthreads();
  }

  const int c = bn + wn * 16 + lr;
  const float b_ir = bih[c], b_iz = bih[1024 + c], b_in = bih[2048 + c];
  const float b_hr = bhh[c], b_hz = bhh[1024 + c], b_hn = bhh[2048 + c];
  #pragma unroll
  for (int m = 0; m < 2; ++m) {
    #pragma unroll
    for (int rr = 0; rr < 4; ++rr) {
      const int row = bm + wm * 32 + m * 16 + lg * 4 + rr;
      const size_t gr = (size_t)row * gi_rs;
      const float pr = gi[gr + c]        + b_ir + acc[0][m][rr] + b_hr;
      const float pz = gi[gr + 1024 + c] + b_iz + acc[1][m][rr] + b_hz;
      const float r = 1.f / (1.f + expf(-pr));
      const float z = 1.f / (1.f + expf(-pz));
      const float n = tanhf(gi[gr + 2048 + c] + b_in + r * (acc[2][m][rr] + b_hn));
      const size_t o = (size_t)row * Hsz + c;
      const float h = (1.f - z) * n + z * hf_in[o];
      hf_out[o] = h;
      const unsigned short hb = f2bf(h);
      hh[o] = hb; hl[o] = f2bf(h - bf2f(hb));
    }
  }
}

// ---------------- attention: pre = h.G + c0, softmax, argmax/flag, outputs -----
__global__ __launch_bounds__(256) void k_attn(
    const float* __restrict__ hf, const float* __restrict__ G,
    const float* __restrict__ c0,
    unsigned int* __restrict__ flag, const unsigned int* __restrict__ valid,
    float* __restrict__ out, int t)
{
  const int b = blockIdx.x;
  __shared__ float pre_s[32];
  __shared__ float top_s[32];
  const int w = threadIdx.x >> 6;
  const int lane = threadIdx.x & 63;

  float qr[16];
  const float4* q4 = (const float4*)(hf + (size_t)b * Hsz);
  #pragma unroll
  for (int i = 0; i < 4; ++i) {
    const float4 v = q4[lane * 4 + i];
    qr[4*i+0] = v.x; qr[4*i+1] = v.y; qr[4*i+2] = v.z; qr[4*i+3] = v.w;
  }

  for (int l = w; l < Lsz; l += 4) {
    const float4* r4 = (const float4*)(G + ((size_t)b * Lsz + l) * Hsz);
    float s = 0.f;
    #pragma unroll
    for (int i = 0; i < 4; ++i) {
      const float4 v = r4[lane * 4 + i];
      s = fmaf(qr[4*i+0], v.x, s);
      s = fmaf(qr[4*i+1], v.y, s);
      s = fmaf(qr[4*i+2], v.z, s);
      s = fmaf(qr[4*i+3], v.w, s);
    }
    #pragma unroll
    for (int off = 32; off >= 1; off >>= 1) s += __shfl_xor(s, off, 64);
    if (lane == 0) pre_s[l] = s + c0[b * Lsz + l];
  }
  __syncthreads();

  if (threadIdx.x == 0) {
    const unsigned int fl = flag[b];
    const unsigned int ex = fl | ~valid[b];
    float best = -3.4e38f; int am = 0;
    for (int l = 0; l < Lsz; ++l) {
      if (!((ex >> l) & 1u)) { const float v = pre_s[l]; if (v > best) { best = v; am = l; } }
    }
    float sum = 0.f;
    for (int l = 0; l < Lsz; ++l) {
      const float e = ((ex >> l) & 1u) ? 0.f : expf(pre_s[l] - best);
      top_s[l] = e; sum += e;
    }
    const float inv = 1.f / sum;
    for (int l = 0; l < Lsz; ++l) top_s[l] *= inv;
    flag[b] = fl | (1u << am);
  }
  __syncthreads();

  if (threadIdx.x < Lsz) {
    const int l = threadIdx.x;
    out[(size_t)b * (Tsz * Lsz) + t * Lsz + l] = pre_s[l];
    out[(size_t)Bsz * Tsz * Lsz + (size_t)b * (Tsz * Lsz) + t * Lsz + l] = top_s[l];
  }
}

extern "C" void kernel_launch(void* const* d_in, const int* in_sizes, int n_in,
                              void* d_out, int out_size, void* d_ws, size_t ws_size,
                              hipStream_t stream) {
  const float* ih  = (const float*)d_in[0];
  const float* tg  = (const float*)d_in[1];
  const int*   pos = (const int*)d_in[2];
  const float* S   = (const float*)d_in[4];
  const float* wih = (const float*)d_in[5];
  const float* whh = (const float*)d_in[6];
  const float* bih = (const float*)d_in[7];
  const float* bhh = (const float*)d_in[8];
  const float* wlw = (const float*)d_in[9];
  const float* wlb = (const float*)d_in[10];
  float* out = (float*)d_out;

  const size_t NW3 = (size_t)3 * Hsz * Hsz;
  const size_t NW1 = (size_t)Hsz * Hsz;
  const size_t NH  = (size_t)Bsz * Hsz;

  char* p = (char*)d_ws;
  unsigned short* wihh = (unsigned short*)p; p += NW3 * 2;
  unsigned short* wihl = (unsigned short*)p; p += NW3 * 2;
  unsigned short* whhh = (unsigned short*)p; p += NW3 * 2;
  unsigned short* whhl = (unsigned short*)p; p += NW3 * 2;
  unsigned short* wlt0 = (unsigned short*)p; p += NW1 * 2;
  unsigned short* wlt1 = (unsigned short*)p; p += NW1 * 2;
  unsigned short* wlt2 = (unsigned short*)p; p += NW1 * 2;
  float* ring = (float*)p; p += (size_t)8 * Bsz * 3072 * 4;       // 50.3 MB
  float* G    = (float*)p; p += (size_t)Bsz * Lsz * Hsz * 4;      // 62.9 MB
  float* c0   = (float*)p; p += (size_t)Bsz * Lsz * 4;
  float* gi0  = (float*)p; p += 3072 * 4;
  float* hf0  = (float*)p; p += NH * 4;
  float* hf1  = (float*)p; p += NH * 4;
  unsigned short* hh0 = (unsigned short*)p; p += NH * 2;
  unsigned short* hl0 = (unsigned short*)p; p += NH * 2;
  unsigned short* hh1 = (unsigned short*)p; p += NH * 2;
  unsigned short* hl1 = (unsigned short*)p; p += NH * 2;
  unsigned int* flag  = (unsigned int*)p; p += Bsz * 4;
  unsigned int* valid = (unsigned int*)p; p += Bsz * 4;

  k_split<<<(int)(NW3 / 4 + 255) / 256, 256, 0, stream>>>(wih, wihh, wihl, (int)(NW3 / 4));
  k_split<<<(int)(NW3 / 4 + 255) / 256, 256, 0, stream>>>(whh, whhh, whhl, (int)(NW3 / 4));
  k_splitT3<<<dim3(32, 32), 256, 0, stream>>>(wlw, wlt0, wlt1, wlt2);
  k_init<<<Bsz, 256, 0, stream>>>(ih, pos, wlb, hf0, hh0, hl0, c0, flag, valid);
  k_gemv0<<<48, 256, 0, stream>>>(S, wih, gi0);
  // G = ih @ Wl  (M=15360, N=1024), 6-pass fp32-grade
  k_gemmG<<<dim3(16, 240), 256, 0, stream>>>(ih, wlt0, wlt1, wlt2, G);

  for (int t = 0; t < Tsz; ++t) {
    if (t == 1 || t == 9 || t == 17 || t == 25) {
      const int ns = (t == 25) ? 5 : 8;
      k_tgemm<<<dim3(24, ns * 4), 256, 0, stream>>>(tg, wihh, wihl, ring, t);
    }
    const float* hfi = (t & 1) ? hf1 : hf0;
    float*       hfo = (t & 1) ? hf0 : hf1;
    const unsigned short* hhi = (t & 1) ? hh1 : hh0;
    const unsigned short* hli = (t & 1) ? hl1 : hl0;
    unsigned short* hho = (t & 1) ? hh0 : hh1;
    unsigned short* hlo = (t & 1) ? hl0 : hl1;

    const float* gip = (t == 0) ? gi0 : (ring + (size_t)(t & 7) * Bsz * 3072);
    k_ghc<<<dim3(32, 8), 256, 0, stream>>>(hhi, hli, whhh, whhl, gip, (t == 0) ? 0 : 3072,
                                           bih, bhh, hfi, hfo, hho, hlo);
    k_attn<<<Bsz, 256, 0, stream>>>(hfo, G, c0, flag, valid, out, t);
  }
}

// Round 8
// 2041.008 us; speedup vs baseline: 2.2759x; 1.1417x over previous
//
#include <hip/hip_runtime.h>

#define Bsz 512
#define Lsz 30
#define Hsz 1024
#define Tsz 30

typedef __bf16 bf16x8 __attribute__((ext_vector_type(8)));
typedef unsigned short u16x8 __attribute__((ext_vector_type(8)));
typedef float  f32x4  __attribute__((ext_vector_type(4)));
typedef unsigned int u32;
typedef unsigned short u16;

__device__ __forceinline__ float bf2f(u16 s) {
  union { u32 u; float f; } v; v.u = ((u32)s) << 16; return v.f;
}
__device__ __forceinline__ u16 f2bf(float f) {
  union { float f; u32 u; } v; v.f = f;
  return (u16)((v.u + 0x7FFFu + ((v.u >> 16) & 1u)) >> 16);
}
__device__ __forceinline__ bf16x8 ld8u(const u16* p) {
  return *reinterpret_cast<const bf16x8*>(p);
}
__device__ __forceinline__ void stage16(const u16* g, u16* l) {
  __builtin_amdgcn_global_load_lds(
      (const __attribute__((address_space(1))) u32*)g,
      (__attribute__((address_space(3))) u32*)l, 16, 0, 0);
}

// ---------------- split fp32 -> (hi, lo) bf16 planes (weights, one-time) -------
__global__ __launch_bounds__(256) void k_split(
    const float* __restrict__ src, u16* __restrict__ hi,
    u16* __restrict__ lo, int n4)
{
  const int i = blockIdx.x * 256 + threadIdx.x;
  if (i >= n4) return;
  const float4 v = ((const float4*)src)[i];
  u16 h0 = f2bf(v.x), h1 = f2bf(v.y), h2 = f2bf(v.z), h3 = f2bf(v.w);
  u16 l0 = f2bf(v.x - bf2f(h0)), l1 = f2bf(v.y - bf2f(h1));
  u16 l2 = f2bf(v.z - bf2f(h2)), l3 = f2bf(v.w - bf2f(h3));
  ((ushort4*)hi)[i] = make_ushort4(h0, h1, h2, h3);
  ((ushort4*)lo)[i] = make_ushort4(l0, l1, l2, l3);
}

// -------- transpose + 3-plane split: out[k][n] = in[n][k] (for Wl) -------------
__global__ __launch_bounds__(256) void k_splitT3(
    const float* __restrict__ src, u16* __restrict__ t0,
    u16* __restrict__ t1, u16* __restrict__ t2)
{
  __shared__ float t[32][33];
  const int tid = threadIdx.x;
  const int bi = blockIdx.x * 32, bj = blockIdx.y * 32;
  const int r = tid >> 3, c4 = (tid & 7) * 4;
  const float4 v = *(const float4*)(src + (size_t)(bi + r) * Hsz + bj + c4);
  t[r][c4] = v.x; t[r][c4 + 1] = v.y; t[r][c4 + 2] = v.z; t[r][c4 + 3] = v.w;
  __syncthreads();
  float f[4] = { t[c4][r], t[c4 + 1][r], t[c4 + 2][r], t[c4 + 3][r] };
  u16 h[4], m[4], l[4];
  #pragma unroll
  for (int i = 0; i < 4; ++i) {
    h[i] = f2bf(f[i]);
    const float r1 = f[i] - bf2f(h[i]);
    m[i] = f2bf(r1);
    l[i] = f2bf(r1 - bf2f(m[i]));
  }
  const size_t o = (size_t)(bj + r) * Hsz + bi + c4;
  *(ushort4*)(t0 + o) = make_ushort4(h[0], h[1], h[2], h[3]);
  *(ushort4*)(t1 + o) = make_ushort4(m[0], m[1], m[2], m[3]);
  *(ushort4*)(t2 + o) = make_ushort4(l[0], l[1], l[2], l[3]);
}

// ---------------- init: h0 = mean_L(ih), h splits, c0 = Wl_b . ih, masks -------
__global__ __launch_bounds__(256) void k_init(
    const float* __restrict__ ih, const int* __restrict__ pos,
    const float* __restrict__ wlb,
    float* __restrict__ hf, u16* __restrict__ hh,
    u16* __restrict__ hl, float* __restrict__ c0,
    u32* __restrict__ flag, u32* __restrict__ valid)
{
  __shared__ float red[4];
  const int b = blockIdx.x, tid = threadIdx.x;
  const int lane = tid & 63, wid = tid >> 6;
  const float4 wb = ((const float4*)wlb)[tid];
  float s0 = 0.f, s1 = 0.f, s2 = 0.f, s3 = 0.f;
  for (int l = 0; l < Lsz; ++l) {
    const float4 v = ((const float4*)(ih + ((size_t)b * Lsz + l) * Hsz))[tid];
    s0 += v.x; s1 += v.y; s2 += v.z; s3 += v.w;
    float part = v.x * wb.x + v.y * wb.y + v.z * wb.z + v.w * wb.w;
    #pragma unroll
    for (int off = 32; off >= 1; off >>= 1) part += __shfl_xor(part, off, 64);
    if (lane == 0) red[wid] = part;
    __syncthreads();
    if (tid == 0) c0[b * Lsz + l] = red[0] + red[1] + red[2] + red[3];
    __syncthreads();
  }
  const size_t o = (size_t)b * Hsz + tid * 4;
  float m[4] = { s0 / 30.f, s1 / 30.f, s2 / 30.f, s3 / 30.f };
  *(float4*)(hf + o) = make_float4(m[0], m[1], m[2], m[3]);
  ushort4 h4, l4;
  h4.x = f2bf(m[0]); h4.y = f2bf(m[1]); h4.z = f2bf(m[2]); h4.w = f2bf(m[3]);
  l4.x = f2bf(m[0] - bf2f(h4.x)); l4.y = f2bf(m[1] - bf2f(h4.y));
  l4.z = f2bf(m[2] - bf2f(h4.z)); l4.w = f2bf(m[3] - bf2f(h4.w));
  *(ushort4*)(hh + o) = h4;
  *(ushort4*)(hl + o) = l4;
  if (tid == 0) {
    int ss = 0;
    for (int l = 0; l < Lsz; ++l) ss += (pos[b * Lsz + l] != -1) ? 1 : 0;
    valid[b] = (ss >= 32) ? 0xFFFFFFFFu : ((1u << ss) - 1u);
    flag[b]  = 0u;
  }
}

// ---------------- gi0 = S @ W_ih^T (fp32 GEMV, 3072 outputs) -------------------
__global__ __launch_bounds__(256) void k_gemv0(
    const float* __restrict__ S, const float* __restrict__ wih,
    float* __restrict__ gi0)
{
  const int n = blockIdx.x * 64 + (threadIdx.x >> 2);
  const int part = threadIdx.x & 3;
  const float4* s4 = (const float4*)S + part * 64;
  const float4* w4 = (const float4*)(wih + (size_t)n * Hsz) + part * 64;
  float s = 0.f;
  #pragma unroll 8
  for (int i = 0; i < 64; ++i) {
    const float4 a = s4[i], b = w4[i];
    s = fmaf(a.x, b.x, s); s = fmaf(a.y, b.y, s);
    s = fmaf(a.z, b.z, s); s = fmaf(a.w, b.w, s);
  }
  s += __shfl_xor(s, 1, 64);
  s += __shfl_xor(s, 2, 64);
  if (part == 0) gi0[n] = s;
}

// ============ GI chunk GEMM: 3-pass, A from fp32 (ROUNDED reg split), dbuf =====
__global__ __launch_bounds__(256) void k_tgemm(
    const float* __restrict__ Afp,
    const u16* __restrict__ Bh, const u16* __restrict__ Bl,
    float* __restrict__ C, int t0)
{
  constexpr int oAh = 0, oAl = 4096, oBh = 8192, oBl = 12288;
  __shared__ u16 lds[2][16384];

  const int tid = threadIdx.x;
  const int w = tid >> 6, lane = tid & 63;
  const int wm = w >> 1, wn = w & 1;
  const int lr = lane & 15, lg = lane >> 4;
  const int bm = blockIdx.y * 128, bn = blockIdx.x * 128;

  const int ar = tid & 127, kh = tid >> 7;
  const long arow = (long)((bm + ar) & 511) * Tsz + (t0 - 1) + ((bm + ar) >> 9);
  const float* aptr = Afp + arow * Hsz + kh * 16;
  const int awo0 = (ar >> 4) * 512 + ((ar & 15) + 32 * kh) * 8;

  const u16* gpB[4]; int bwo[4];
  #pragma unroll
  for (int i = 0; i < 4; ++i) {
    const int cid = (w << 2) | i;
    const u16* base; int g, off;
    if (cid < 8) { base = Bh; g = cid;     off = oBh + g * 512; }
    else         { base = Bl; g = cid - 8; off = oBl + g * 512; }
    gpB[i] = base + (size_t)(bn + g * 16 + lr) * Hsz + lg * 8;
    bwo[i] = off;
  }

  float4 areg[4];
  #define LOAD_A() { _Pragma("unroll") for (int i = 0; i < 4; ++i) areg[i] = ((const float4*)aptr)[i]; aptr += 32; }
  #define STAGE_B(buf) { _Pragma("unroll") for (int i = 0; i < 4; ++i) { stage16(gpB[i], &lds[buf][bwo[i]]); gpB[i] += 32; } }
  #define WRITE_A(buf) { \
    u16x8 h0v, h1v, l0v, l1v; \
    _Pragma("unroll") for (int i = 0; i < 4; ++i) { \
      const float f[4] = { areg[i].x, areg[i].y, areg[i].z, areg[i].w }; \
      _Pragma("unroll") for (int c = 0; c < 4; ++c) { \
        const int j = 4 * i + c; \
        const u16 hb = f2bf(f[c]); \
        const u16 lb = f2bf(f[c] - bf2f(hb)); \
        if (j < 8) { h0v[j] = hb; l0v[j] = lb; } else { h1v[j - 8] = hb; l1v[j - 8] = lb; } \
      } \
    } \
    *(u16x8*)&lds[buf][oAh + awo0]       = h0v; \
    *(u16x8*)&lds[buf][oAh + awo0 + 128] = h1v; \
    *(u16x8*)&lds[buf][oAl + awo0]       = l0v; \
    *(u16x8*)&lds[buf][oAl + awo0 + 128] = l1v; }

  f32x4 acc[4][4] = {};

  LOAD_A();
  STAGE_B(0);
  WRITE_A(0);
  __syncthreads();

  for (int ks = 0; ks < 32; ++ks) {
    const int cur = ks & 1;
    if (ks < 31) { STAGE_B(cur ^ 1); LOAD_A(); }
    {
      const u16* L = &lds[cur][0];
      bf16x8 a_h[4], a_l[4], b_h[4], b_l[4];
      #pragma unroll
      for (int m = 0; m < 4; ++m) {
        const int g = wm * 4 + m;
        a_h[m] = ld8u(L + oAh + g * 512 + lane * 8);
        a_l[m] = ld8u(L + oAl + g * 512 + lane * 8);
      }
      #pragma unroll
      for (int n = 0; n < 4; ++n) {
        const int g = wn * 4 + n;
        b_h[n] = ld8u(L + oBh + g * 512 + lane * 8);
        b_l[n] = ld8u(L + oBl + g * 512 + lane * 8);
      }
      #pragma unroll
      for (int m = 0; m < 4; ++m)
        #pragma unroll
        for (int n = 0; n < 4; ++n) {
          acc[m][n] = __builtin_amdgcn_mfma_f32_16x16x32_bf16(a_h[m], b_h[n], acc[m][n], 0, 0, 0);
          acc[m][n] = __builtin_amdgcn_mfma_f32_16x16x32_bf16(a_h[m], b_l[n], acc[m][n], 0, 0, 0);
          acc[m][n] = __builtin_amdgcn_mfma_f32_16x16x32_bf16(a_l[m], b_h[n], acc[m][n], 0, 0, 0);
        }
    }
    __syncthreads();
    if (ks < 31) { WRITE_A(cur ^ 1); __syncthreads(); }
  }

  #pragma unroll
  for (int n = 0; n < 4; ++n) {
    const int col = bn + wn * 64 + n * 16 + lr;
    #pragma unroll
    for (int m = 0; m < 4; ++m) {
      #pragma unroll
      for (int rr = 0; rr < 4; ++rr) {
        const int row = bm + wm * 64 + m * 16 + lg * 4 + rr;
        const int slot = (t0 + (row >> 9)) & 7;
        C[((size_t)slot * Bsz + (row & 511)) * 3072 + col] = acc[m][n][rr];
      }
    }
  }
  #undef LOAD_A
  #undef STAGE_B
  #undef WRITE_A
}

// ============ G = ih @ WlT : 3-plane split, 6-pass (fp32-grade) ================
__global__ __launch_bounds__(256) void k_gemmG(
    const float* __restrict__ Afp,
    const u16* __restrict__ B0, const u16* __restrict__ B1,
    const u16* __restrict__ B2, float* __restrict__ C)
{
  __shared__ u16 lds[12288];

  const int tid = threadIdx.x;
  const int w = tid >> 6, lane = tid & 63;
  const int wm = w >> 1, wn = w & 1;
  const int lr = lane & 15, lg = lane >> 4;
  const int bm = blockIdx.y * 64, bn = blockIdx.x * 64;

  const int ar = tid & 63, kh = tid >> 6;
  const float* aptr = Afp + (size_t)(bm + ar) * Hsz + kh * 8;
  const int awo = (ar >> 4) * 512 + ((ar & 15) + 16 * kh) * 8;

  const u16* gpB[3]; int bwo[3];
  #pragma unroll
  for (int i = 0; i < 3; ++i) {
    const int cid = w * 3 + i;
    const int p = cid >> 2, g = cid & 3;
    const u16* base = (p == 0) ? B0 : (p == 1) ? B1 : B2;
    gpB[i] = base + (size_t)(bn + g * 16 + lr) * Hsz + lg * 8;
    bwo[i] = 6144 + p * 2048 + g * 512;
  }

  f32x4 acc[2][2] = {};

  for (int ks = 0; ks < 32; ++ks) {
    const float4 va = ((const float4*)aptr)[0];
    const float4 vb = ((const float4*)aptr)[1];
    aptr += 32;
    u16x8 p0, p1, p2;
    {
      const float f[8] = { va.x, va.y, va.z, va.w, vb.x, vb.y, vb.z, vb.w };
      #pragma unroll
      for (int j = 0; j < 8; ++j) {
        const u16 h = f2bf(f[j]);
        const float r1 = f[j] - bf2f(h);
        const u16 m_ = f2bf(r1);
        const u16 l_ = f2bf(r1 - bf2f(m_));
        p0[j] = h; p1[j] = m_; p2[j] = l_;
      }
    }
    #pragma unroll
    for (int i = 0; i < 3; ++i) { stage16(gpB[i], &lds[bwo[i]]); gpB[i] += 32; }
    *(u16x8*)&lds[awo]        = p0;
    *(u16x8*)&lds[2048 + awo] = p1;
    *(u16x8*)&lds[4096 + awo] = p2;
    __syncthreads();

    bf16x8 ap[3][2], bp[3][2];
    #pragma unroll
    for (int p = 0; p < 3; ++p)
      #pragma unroll
      for (int m = 0; m < 2; ++m) {
        ap[p][m] = ld8u(&lds[p * 2048 + (wm * 2 + m) * 512 + lane * 8]);
        bp[p][m] = ld8u(&lds[6144 + p * 2048 + (wn * 2 + m) * 512 + lane * 8]);
      }
    #pragma unroll
    for (int m = 0; m < 2; ++m)
      #pragma unroll
      for (int n = 0; n < 2; ++n) {
        acc[m][n] = __builtin_amdgcn_mfma_f32_16x16x32_bf16(ap[0][m], bp[0][n], acc[m][n], 0, 0, 0);
        acc[m][n] = __builtin_amdgcn_mfma_f32_16x16x32_bf16(ap[0][m], bp[1][n], acc[m][n], 0, 0, 0);
        acc[m][n] = __builtin_amdgcn_mfma_f32_16x16x32_bf16(ap[1][m], bp[0][n], acc[m][n], 0, 0, 0);
        acc[m][n] = __builtin_amdgcn_mfma_f32_16x16x32_bf16(ap[0][m], bp[2][n], acc[m][n], 0, 0, 0);
        acc[m][n] = __builtin_amdgcn_mfma_f32_16x16x32_bf16(ap[1][m], bp[1][n], acc[m][n], 0, 0, 0);
        acc[m][n] = __builtin_amdgcn_mfma_f32_16x16x32_bf16(ap[2][m], bp[0][n], acc[m][n], 0, 0, 0);
      }
    __syncthreads();
  }

  #pragma unroll
  for (int n = 0; n < 2; ++n) {
    const int col = bn + wn * 32 + n * 16 + lr;
    #pragma unroll
    for (int m = 0; m < 2; ++m) {
      #pragma unroll
      for (int rr = 0; rr < 4; ++rr) {
        const int row = bm + wm * 32 + m * 16 + lg * 4 + rr;
        C[(size_t)row * Hsz + col] = acc[m][n][rr];
      }
    }
  }
}

// ============ device bodies: ghc (8-wave) and attn =============================
__device__ __forceinline__ void ghc_body(
    const u16* __restrict__ Hh, const u16* __restrict__ Hl,
    const u16* __restrict__ Wh, const u16* __restrict__ Wl,
    const float* __restrict__ gi, int gi_rs,
    const float* __restrict__ bih, const float* __restrict__ bhh,
    const float* __restrict__ hf_in, float* __restrict__ hf_out,
    u16* __restrict__ hho, u16* __restrict__ hlo, int bm, int bn)
{
  constexpr int oAh = 0, oAl = 2048, oBh = 4096, oBl = 7168;
  __shared__ u16 lds[2][10240];

  const int tid = threadIdx.x;
  const int w = tid >> 6, lane = tid & 63;
  const int wm = w >> 1, wn = w & 1;          // wm 0..3 (16-row frag), wn 0..1 (16-col group)
  const int lr = lane & 15, lg = lane >> 4;

  // 20 chunks over 8 waves: wave w takes cid = w, w+8, (w<4: w+16)
  const u16* gp[3]; int ldso[3];
  const int nch = (w < 4) ? 3 : 2;
  #pragma unroll
  for (int i = 0; i < 3; ++i) {
    const int cid = w + 8 * i;
    if (cid >= 20) break;
    const u16* base; long row; int off;
    if (cid < 4)       { const int g = cid;      row = bm + g * 16 + lr;                         base = Hh; off = oAh + g * 512; }
    else if (cid < 8)  { const int g = cid - 4;  row = bm + g * 16 + lr;                         base = Hl; off = oAl + g * 512; }
    else if (cid < 14) { const int g = cid - 8;  row = (g >> 1) * 1024 + bn + (g & 1) * 16 + lr; base = Wh; off = oBh + g * 512; }
    else               { const int g = cid - 14; row = (g >> 1) * 1024 + bn + (g & 1) * 16 + lr; base = Wl; off = oBl + g * 512; }
    gp[i] = base + row * Hsz + lg * 8;
    ldso[i] = off;
  }

  f32x4 acc[3] = {};   // r, z, n gates for this wave's 16x16 tile

  for (int i = 0; i < nch; ++i) { stage16(gp[i], &lds[0][ldso[i]]); gp[i] += 32; }
  __syncthreads();

  for (int ks = 0; ks < 32; ++ks) {
    const int cur = ks & 1;
    if (ks < 31) {
      for (int i = 0; i < nch; ++i) { stage16(gp[i], &lds[cur ^ 1][ldso[i]]); gp[i] += 32; }
    }
    const u16* L = &lds[cur][0];
    const bf16x8 ah = ld8u(L + oAh + wm * 512 + lane * 8);
    const bf16x8 al = ld8u(L + oAl + wm * 512 + lane * 8);
    #pragma unroll
    for (int gt = 0; gt < 3; ++gt) {
      const int g = gt * 2 + wn;
      const bf16x8 bh = ld8u(L + oBh + g * 512 + lane * 8);
      const bf16x8 bl = ld8u(L + oBl + g * 512 + lane * 8);
      acc[gt] = __builtin_amdgcn_mfma_f32_16x16x32_bf16(ah, bh, acc[gt], 0, 0, 0);
      acc[gt] = __builtin_amdgcn_mfma_f32_16x16x32_bf16(ah, bl, acc[gt], 0, 0, 0);
      acc[gt] = __builtin_amdgcn_mfma_f32_16x16x32_bf16(al, bh, acc[gt], 0, 0, 0);
    }
    __syncthreads();
  }

  const int c = bn + wn * 16 + lr;
  const float b_ir = bih[c], b_iz = bih[1024 + c], b_in = bih[2048 + c];
  const float b_hr = bhh[c], b_hz = bhh[1024 + c], b_hn = bhh[2048 + c];
  #pragma unroll
  for (int rr = 0; rr < 4; ++rr) {
    const int row = bm + wm * 16 + lg * 4 + rr;
    const size_t gr = (size_t)row * gi_rs;
    const float pr = gi[gr + c]        + b_ir + acc[0][rr] + b_hr;
    const float pz = gi[gr + 1024 + c] + b_iz + acc[1][rr] + b_hz;
    const float r = 1.f / (1.f + expf(-pr));
    const float z = 1.f / (1.f + expf(-pz));
    const float n = tanhf(gi[gr + 2048 + c] + b_in + r * (acc[2][rr] + b_hn));
    const size_t o = (size_t)row * Hsz + c;
    const float h = (1.f - z) * n + z * hf_in[o];
    hf_out[o] = h;
    const u16 hb = f2bf(h);
    hho[o] = hb; hlo[o] = f2bf(h - bf2f(hb));
  }
}

__device__ __forceinline__ void attn_body(
    const float* __restrict__ hf, const float* __restrict__ G,
    const float* __restrict__ c0,
    u32* __restrict__ flag, const u32* __restrict__ valid,
    float* __restrict__ out, int t, int b)
{
  __shared__ float pre_s[32];
  __shared__ float top_s[32];
  const int w = threadIdx.x >> 6;        // 8 waves
  const int lane = threadIdx.x & 63;

  float qr[16];
  const float4* q4 = (const float4*)(hf + (size_t)b * Hsz);
  #pragma unroll
  for (int i = 0; i < 4; ++i) {
    const float4 v = q4[lane * 4 + i];
    qr[4*i+0] = v.x; qr[4*i+1] = v.y; qr[4*i+2] = v.z; qr[4*i+3] = v.w;
  }

  for (int l = w; l < Lsz; l += 8) {
    const float4* r4 = (const float4*)(G + ((size_t)b * Lsz + l) * Hsz);
    float s = 0.f;
    #pragma unroll
    for (int i = 0; i < 4; ++i) {
      const float4 v = r4[lane * 4 + i];
      s = fmaf(qr[4*i+0], v.x, s);
      s = fmaf(qr[4*i+1], v.y, s);
      s = fmaf(qr[4*i+2], v.z, s);
      s = fmaf(qr[4*i+3], v.w, s);
    }
    #pragma unroll
    for (int off = 32; off >= 1; off >>= 1) s += __shfl_xor(s, off, 64);
    if (lane == 0) pre_s[l] = s + c0[b * Lsz + l];
  }
  __syncthreads();

  if (threadIdx.x == 0) {
    const u32 fl = flag[b];
    const u32 ex = fl | ~valid[b];
    float best = -3.4e38f; int am = 0;
    for (int l = 0; l < Lsz; ++l) {
      if (!((ex >> l) & 1u)) { const float v = pre_s[l]; if (v > best) { best = v; am = l; } }
    }
    float sum = 0.f;
    for (int l = 0; l < Lsz; ++l) {
      const float e = ((ex >> l) & 1u) ? 0.f : expf(pre_s[l] - best);
      top_s[l] = e; sum += e;
    }
    const float inv = 1.f / sum;
    for (int l = 0; l < Lsz; ++l) top_s[l] *= inv;
    flag[b] = fl | (1u << am);
  }
  __syncthreads();

  if (threadIdx.x < Lsz) {
    const int l = threadIdx.x;
    out[(size_t)b * (Tsz * Lsz) + t * Lsz + l] = pre_s[l];
    out[(size_t)Bsz * Tsz * Lsz + (size_t)b * (Tsz * Lsz) + t * Lsz + l] = top_s[l];
  }
}

// ghc[0] standalone
__global__ __launch_bounds__(512) void k_ghc0(
    const u16* Hh, const u16* Hl, const u16* Wh, const u16* Wl,
    const float* gi, int gi_rs, const float* bih, const float* bhh,
    const float* hf_in, float* hf_out, u16* hho, u16* hlo)
{
  const int bn = (blockIdx.x & 31) * 32, bm = (blockIdx.x >> 5) * 64;
  ghc_body(Hh, Hl, Wh, Wl, gi, gi_rs, bih, bhh, hf_in, hf_out, hho, hlo, bm, bn);
}

// fused: attn[t] (blocks 256..767) + ghc[t+1] (blocks 0..255, if do_ghc)
__global__ __launch_bounds__(512) void k_step(
    const float* hf_t, const u16* hh_t, const u16* hl_t,
    float* hf_n, u16* hh_n, u16* hl_n,
    const u16* Wh, const u16* Wl,
    const float* gi, const float* bih, const float* bhh,
    const float* G, const float* c0,
    u32* flag, const u32* valid, float* out, int t, int do_ghc)
{
  if (blockIdx.x < 256) {
    if (!do_ghc) return;
    const int bn = (blockIdx.x & 31) * 32, bm = (blockIdx.x >> 5) * 64;
    ghc_body(hh_t, hl_t, Wh, Wl, gi, 3072, bih, bhh, hf_t, hf_n, hh_n, hl_n, bm, bn);
  } else {
    attn_body(hf_t, G, c0, flag, valid, out, t, blockIdx.x - 256);
  }
}

extern "C" void kernel_launch(void* const* d_in, const int* in_sizes, int n_in,
                              void* d_out, int out_size, void* d_ws, size_t ws_size,
                              hipStream_t stream) {
  const float* ih  = (const float*)d_in[0];
  const float* tg  = (const float*)d_in[1];
  const int*   pos = (const int*)d_in[2];
  const float* S   = (const float*)d_in[4];
  const float* wih = (const float*)d_in[5];
  const float* whh = (const float*)d_in[6];
  const float* bih = (const float*)d_in[7];
  const float* bhh = (const float*)d_in[8];
  const float* wlw = (const float*)d_in[9];
  const float* wlb = (const float*)d_in[10];
  float* out = (float*)d_out;

  const size_t NW3 = (size_t)3 * Hsz * Hsz;
  const size_t NW1 = (size_t)Hsz * Hsz;
  const size_t NH  = (size_t)Bsz * Hsz;

  char* p = (char*)d_ws;
  u16* wihh = (u16*)p; p += NW3 * 2;
  u16* wihl = (u16*)p; p += NW3 * 2;
  u16* whhh = (u16*)p; p += NW3 * 2;
  u16* whhl = (u16*)p; p += NW3 * 2;
  u16* wlt0 = (u16*)p; p += NW1 * 2;
  u16* wlt1 = (u16*)p; p += NW1 * 2;
  u16* wlt2 = (u16*)p; p += NW1 * 2;
  float* ring = (float*)p; p += (size_t)8 * Bsz * 3072 * 4;
  float* G    = (float*)p; p += (size_t)Bsz * Lsz * Hsz * 4;
  float* c0   = (float*)p; p += (size_t)Bsz * Lsz * 4;
  float* gi0  = (float*)p; p += 3072 * 4;
  float* hfb[2]; u16* hhb[2]; u16* hlb[2];
  hfb[0] = (float*)p; p += NH * 4;
  hfb[1] = (float*)p; p += NH * 4;
  hhb[0] = (u16*)p; p += NH * 2;
  hlb[0] = (u16*)p; p += NH * 2;
  hhb[1] = (u16*)p; p += NH * 2;
  hlb[1] = (u16*)p; p += NH * 2;
  u32* flag  = (u32*)p; p += Bsz * 4;
  u32* valid = (u32*)p; p += Bsz * 4;

  k_split<<<(int)(NW3 / 4 + 255) / 256, 256, 0, stream>>>(wih, wihh, wihl, (int)(NW3 / 4));
  k_split<<<(int)(NW3 / 4 + 255) / 256, 256, 0, stream>>>(whh, whhh, whhl, (int)(NW3 / 4));
  k_splitT3<<<dim3(32, 32), 256, 0, stream>>>(wlw, wlt0, wlt1, wlt2);
  k_init<<<Bsz, 256, 0, stream>>>(ih, pos, wlb, hfb[0], hhb[0], hlb[0], c0, flag, valid);
  k_gemv0<<<48, 256, 0, stream>>>(S, wih, gi0);
  k_gemmG<<<dim3(16, 240), 256, 0, stream>>>(ih, wlt0, wlt1, wlt2, G);

  // h[0]: ghc with gi0 (stride 0); h[-1]=h0 in buf0, h[0] -> buf1
  k_ghc0<<<256, 512, 0, stream>>>(hhb[0], hlb[0], whhh, whhl, gi0, 0, bih, bhh,
                                  hfb[0], hfb[1], hhb[1], hlb[1]);

  for (int t = 0; t < Tsz; ++t) {
    const int tn = t + 1;
    if (tn == 1 || tn == 9 || tn == 17 || tn == 25) {
      const int ns = (tn == 25) ? 5 : 8;
      k_tgemm<<<dim3(24, ns * 4), 256, 0, stream>>>(tg, wihh, wihl, ring, tn);
    }
    const int ci = tn & 1;        // h[t] buffer
    const int ni = t & 1;         // h[t+1] buffer
    const int do_ghc = (t < Tsz - 1) ? 1 : 0;
    k_step<<<768, 512, 0, stream>>>(hfb[ci], hhb[ci], hlb[ci],
                                    hfb[ni], hhb[ni], hlb[ni],
                                    whhh, whhl,
                                    ring + (size_t)(tn & 7) * Bsz * 3072,
                                    bih, bhh, G, c0, flag, valid, out, t, do_ghc);
  }
}

// Round 9
// 1859.342 us; speedup vs baseline: 2.4983x; 1.0977x over previous
//
#include <hip/hip_runtime.h>

#define Bsz 512
#define Lsz 30
#define Hsz 1024
#define Tsz 30

typedef _Float16 f16;
typedef f16 f16x8 __attribute__((ext_vector_type(8)));
typedef unsigned short u16x8 __attribute__((ext_vector_type(8)));
typedef float  f32x4  __attribute__((ext_vector_type(4)));
typedef unsigned int u32;
typedef unsigned short u16;

#define WSCALE 32.0f
#define INVWS  0.03125f

__device__ __forceinline__ u16 h2u(f16 h) {
  union { f16 h; u16 u; } v; v.h = h; return v.u;
}
__device__ __forceinline__ f16x8 ld8h(const u16* p) {
  return *reinterpret_cast<const f16x8*>(p);
}
__device__ __forceinline__ void stage16(const u16* g, u16* l) {
  __builtin_amdgcn_global_load_lds(
      (const __attribute__((address_space(1))) u32*)g,
      (__attribute__((address_space(3))) u32*)l, 16, 0, 0);
}

// ------- split fp32 -> (hi, lo) fp16 planes, pre-scaled by WSCALE (weights) ----
__global__ __launch_bounds__(256) void k_split(
    const float* __restrict__ src, u16* __restrict__ hi,
    u16* __restrict__ lo, int n4)
{
  const int i = blockIdx.x * 256 + threadIdx.x;
  if (i >= n4) return;
  const float4 v = ((const float4*)src)[i];
  const float f[4] = { v.x * WSCALE, v.y * WSCALE, v.z * WSCALE, v.w * WSCALE };
  u16 h[4], l[4];
  #pragma unroll
  for (int j = 0; j < 4; ++j) {
    const f16 hb = (f16)f[j];
    const f16 lb = (f16)(f[j] - (float)hb);
    h[j] = h2u(hb); l[j] = h2u(lb);
  }
  ((ushort4*)hi)[i] = make_ushort4(h[0], h[1], h[2], h[3]);
  ((ushort4*)lo)[i] = make_ushort4(l[0], l[1], l[2], l[3]);
}

// -------- transpose + scaled fp16 2-plane split: out[k][n] = in[n][k] (Wl) -----
__global__ __launch_bounds__(256) void k_splitT2(
    const float* __restrict__ src, u16* __restrict__ t0, u16* __restrict__ t1)
{
  __shared__ float t[32][33];
  const int tid = threadIdx.x;
  const int bi = blockIdx.x * 32, bj = blockIdx.y * 32;
  const int r = tid >> 3, c4 = (tid & 7) * 4;
  const float4 v = *(const float4*)(src + (size_t)(bi + r) * Hsz + bj + c4);
  t[r][c4] = v.x; t[r][c4 + 1] = v.y; t[r][c4 + 2] = v.z; t[r][c4 + 3] = v.w;
  __syncthreads();
  u16 h[4], l[4];
  #pragma unroll
  for (int i = 0; i < 4; ++i) {
    const float f = t[c4 + i][r] * WSCALE;
    const f16 hb = (f16)f;
    const f16 lb = (f16)(f - (float)hb);
    h[i] = h2u(hb); l[i] = h2u(lb);
  }
  const size_t o = (size_t)(bj + r) * Hsz + bi + c4;
  *(ushort4*)(t0 + o) = make_ushort4(h[0], h[1], h[2], h[3]);
  *(ushort4*)(t1 + o) = make_ushort4(l[0], l[1], l[2], l[3]);
}

// ---------------- init: h0 = mean_L(ih), h fp16 splits, c0 = Wl_b . ih, masks --
__global__ __launch_bounds__(256) void k_init(
    const float* __restrict__ ih, const int* __restrict__ pos,
    const float* __restrict__ wlb,
    float* __restrict__ hf, u16* __restrict__ hh,
    u16* __restrict__ hl, float* __restrict__ c0,
    u32* __restrict__ flag, u32* __restrict__ valid)
{
  __shared__ float red[4];
  const int b = blockIdx.x, tid = threadIdx.x;
  const int lane = tid & 63, wid = tid >> 6;
  const float4 wb = ((const float4*)wlb)[tid];
  float s0 = 0.f, s1 = 0.f, s2 = 0.f, s3 = 0.f;
  for (int l = 0; l < Lsz; ++l) {
    const float4 v = ((const float4*)(ih + ((size_t)b * Lsz + l) * Hsz))[tid];
    s0 += v.x; s1 += v.y; s2 += v.z; s3 += v.w;
    float part = v.x * wb.x + v.y * wb.y + v.z * wb.z + v.w * wb.w;
    #pragma unroll
    for (int off = 32; off >= 1; off >>= 1) part += __shfl_xor(part, off, 64);
    if (lane == 0) red[wid] = part;
    __syncthreads();
    if (tid == 0) c0[b * Lsz + l] = red[0] + red[1] + red[2] + red[3];
    __syncthreads();
  }
  const size_t o = (size_t)b * Hsz + tid * 4;
  const float m[4] = { s0 / 30.f, s1 / 30.f, s2 / 30.f, s3 / 30.f };
  *(float4*)(hf + o) = make_float4(m[0], m[1], m[2], m[3]);
  u16 h4[4], l4[4];
  #pragma unroll
  for (int j = 0; j < 4; ++j) {
    const f16 hb = (f16)m[j];
    const f16 lb = (f16)(m[j] - (float)hb);
    h4[j] = h2u(hb); l4[j] = h2u(lb);
  }
  *(ushort4*)(hh + o) = make_ushort4(h4[0], h4[1], h4[2], h4[3]);
  *(ushort4*)(hl + o) = make_ushort4(l4[0], l4[1], l4[2], l4[3]);
  if (tid == 0) {
    int ss = 0;
    for (int l = 0; l < Lsz; ++l) ss += (pos[b * Lsz + l] != -1) ? 1 : 0;
    valid[b] = (ss >= 32) ? 0xFFFFFFFFu : ((1u << ss) - 1u);
    flag[b]  = 0u;
  }
}

// ---------------- gi0 = S @ W_ih^T (fp32 GEMV, 3072 outputs) -------------------
__global__ __launch_bounds__(256) void k_gemv0(
    const float* __restrict__ S, const float* __restrict__ wih,
    float* __restrict__ gi0)
{
  const int n = blockIdx.x * 64 + (threadIdx.x >> 2);
  const int part = threadIdx.x & 3;
  const float4* s4 = (const float4*)S + part * 64;
  const float4* w4 = (const float4*)(wih + (size_t)n * Hsz) + part * 64;
  float s = 0.f;
  #pragma unroll 8
  for (int i = 0; i < 64; ++i) {
    const float4 a = s4[i], b = w4[i];
    s = fmaf(a.x, b.x, s); s = fmaf(a.y, b.y, s);
    s = fmaf(a.z, b.z, s); s = fmaf(a.w, b.w, s);
  }
  s += __shfl_xor(s, 1, 64);
  s += __shfl_xor(s, 2, 64);
  if (part == 0) gi0[n] = s;
}

// ============ 3-pass fp16 GEMM, A reg-split from fp32, dbuf LDS ================
// 128x128 tile, BK=32, 256 thr (4 waves 2x2).
// MODE1 (GI): A-row remap into tgt, C into 8-slot ring [slot][512][3072].
// MODE0 (G):  A rows plain, C[row*ldc + col]. Both scale acc by 1/WSCALE.
template<int MODE>
__global__ __launch_bounds__(256) void k_tgemm(
    const float* __restrict__ Afp,
    const u16* __restrict__ Bh, const u16* __restrict__ Bl,
    float* __restrict__ C, int ldc, int t0)
{
  constexpr int oAh = 0, oAl = 4096, oBh = 8192, oBl = 12288;
  __shared__ u16 lds[2][16384];

  const int tid = threadIdx.x;
  const int w = tid >> 6, lane = tid & 63;
  const int wm = w >> 1, wn = w & 1;
  const int lr = lane & 15, lg = lane >> 4;
  const int bm = blockIdx.y * 128, bn = blockIdx.x * 128;

  const int ar = tid & 127, kh = tid >> 7;
  long arow;
  if (MODE == 1) arow = (long)((bm + ar) & 511) * Tsz + (t0 - 1) + ((bm + ar) >> 9);
  else           arow = bm + ar;
  const float* aptr = Afp + arow * Hsz + kh * 16;
  const int awo0 = (ar >> 4) * 512 + ((ar & 15) + 32 * kh) * 8;

  const u16* gpB[4]; int bwo[4];
  #pragma unroll
  for (int i = 0; i < 4; ++i) {
    const int cid = (w << 2) | i;
    const u16* base; int g, off;
    if (cid < 8) { base = Bh; g = cid;     off = oBh + g * 512; }
    else         { base = Bl; g = cid - 8; off = oBl + g * 512; }
    gpB[i] = base + (size_t)(bn + g * 16 + lr) * Hsz + lg * 8;
    bwo[i] = off;
  }

  float4 areg[4];
  #define LOAD_A() { _Pragma("unroll") for (int i = 0; i < 4; ++i) areg[i] = ((const float4*)aptr)[i]; aptr += 32; }
  #define STAGE_B(buf) { _Pragma("unroll") for (int i = 0; i < 4; ++i) { stage16(gpB[i], &lds[buf][bwo[i]]); gpB[i] += 32; } }
  #define WRITE_A(buf) { \
    u16x8 h0v, h1v, l0v, l1v; \
    _Pragma("unroll") for (int i = 0; i < 4; ++i) { \
      const float f[4] = { areg[i].x, areg[i].y, areg[i].z, areg[i].w }; \
      _Pragma("unroll") for (int c = 0; c < 4; ++c) { \
        const int j = 4 * i + c; \
        const f16 hb = (f16)f[c]; \
        const f16 lb = (f16)(f[c] - (float)hb); \
        if (j < 8) { h0v[j] = h2u(hb); l0v[j] = h2u(lb); } \
        else       { h1v[j - 8] = h2u(hb); l1v[j - 8] = h2u(lb); } \
      } \
    } \
    *(u16x8*)&lds[buf][oAh + awo0]       = h0v; \
    *(u16x8*)&lds[buf][oAh + awo0 + 128] = h1v; \
    *(u16x8*)&lds[buf][oAl + awo0]       = l0v; \
    *(u16x8*)&lds[buf][oAl + awo0 + 128] = l1v; }

  f32x4 acc[4][4] = {};

  LOAD_A();
  STAGE_B(0);
  WRITE_A(0);
  __syncthreads();

  for (int ks = 0; ks < 32; ++ks) {
    const int cur = ks & 1;
    if (ks < 31) { STAGE_B(cur ^ 1); LOAD_A(); }
    {
      const u16* L = &lds[cur][0];
      f16x8 a_h[4], a_l[4], b_h[4], b_l[4];
      #pragma unroll
      for (int m = 0; m < 4; ++m) {
        const int g = wm * 4 + m;
        a_h[m] = ld8h(L + oAh + g * 512 + lane * 8);
        a_l[m] = ld8h(L + oAl + g * 512 + lane * 8);
      }
      #pragma unroll
      for (int n = 0; n < 4; ++n) {
        const int g = wn * 4 + n;
        b_h[n] = ld8h(L + oBh + g * 512 + lane * 8);
        b_l[n] = ld8h(L + oBl + g * 512 + lane * 8);
      }
      #pragma unroll
      for (int m = 0; m < 4; ++m)
        #pragma unroll
        for (int n = 0; n < 4; ++n) {
          acc[m][n] = __builtin_amdgcn_mfma_f32_16x16x32_f16(a_h[m], b_h[n], acc[m][n], 0, 0, 0);
          acc[m][n] = __builtin_amdgcn_mfma_f32_16x16x32_f16(a_h[m], b_l[n], acc[m][n], 0, 0, 0);
          acc[m][n] = __builtin_amdgcn_mfma_f32_16x16x32_f16(a_l[m], b_h[n], acc[m][n], 0, 0, 0);
        }
    }
    __syncthreads();
    if (ks < 31) { WRITE_A(cur ^ 1); __syncthreads(); }
  }

  #pragma unroll
  for (int n = 0; n < 4; ++n) {
    const int col = bn + wn * 64 + n * 16 + lr;
    #pragma unroll
    for (int m = 0; m < 4; ++m) {
      #pragma unroll
      for (int rr = 0; rr < 4; ++rr) {
        const int row = bm + wm * 64 + m * 16 + lg * 4 + rr;
        const float v = acc[m][n][rr] * INVWS;
        if (MODE == 1) {
          const int slot = (t0 + (row >> 9)) & 7;
          C[((size_t)slot * Bsz + (row & 511)) * 3072 + col] = v;
        } else {
          C[(size_t)row * ldc + col] = v;
        }
      }
    }
  }
  #undef LOAD_A
  #undef STAGE_B
  #undef WRITE_A
}

// ============ device bodies: ghc (8-wave, fp16 3-pass) and attn ================
__device__ __forceinline__ void ghc_body(
    const u16* __restrict__ Hh, const u16* __restrict__ Hl,
    const u16* __restrict__ Wh, const u16* __restrict__ Wl,
    const float* __restrict__ gi, int gi_rs,
    const float* __restrict__ bih, const float* __restrict__ bhh,
    const float* __restrict__ hf_in, float* __restrict__ hf_out,
    u16* __restrict__ hho, u16* __restrict__ hlo, int bm, int bn)
{
  constexpr int oAh = 0, oAl = 2048, oBh = 4096, oBl = 7168;
  __shared__ u16 lds[2][10240];

  const int tid = threadIdx.x;
  const int w = tid >> 6, lane = tid & 63;
  const int wm = w >> 1, wn = w & 1;
  const int lr = lane & 15, lg = lane >> 4;

  const u16* gp[3]; int ldso[3];
  const int nch = (w < 4) ? 3 : 2;
  #pragma unroll
  for (int i = 0; i < 3; ++i) {
    const int cid = w + 8 * i;
    if (cid >= 20) break;
    const u16* base; long row; int off;
    if (cid < 4)       { const int g = cid;      row = bm + g * 16 + lr;                         base = Hh; off = oAh + g * 512; }
    else if (cid < 8)  { const int g = cid - 4;  row = bm + g * 16 + lr;                         base = Hl; off = oAl + g * 512; }
    else if (cid < 14) { const int g = cid - 8;  row = (g >> 1) * 1024 + bn + (g & 1) * 16 + lr; base = Wh; off = oBh + g * 512; }
    else               { const int g = cid - 14; row = (g >> 1) * 1024 + bn + (g & 1) * 16 + lr; base = Wl; off = oBl + g * 512; }
    gp[i] = base + row * Hsz + lg * 8;
    ldso[i] = off;
  }

  f32x4 acc[3] = {};

  for (int i = 0; i < nch; ++i) { stage16(gp[i], &lds[0][ldso[i]]); gp[i] += 32; }
  __syncthreads();

  for (int ks = 0; ks < 32; ++ks) {
    const int cur = ks & 1;
    if (ks < 31) {
      for (int i = 0; i < nch; ++i) { stage16(gp[i], &lds[cur ^ 1][ldso[i]]); gp[i] += 32; }
    }
    const u16* L = &lds[cur][0];
    const f16x8 ah = ld8h(L + oAh + wm * 512 + lane * 8);
    const f16x8 al = ld8h(L + oAl + wm * 512 + lane * 8);
    #pragma unroll
    for (int gt = 0; gt < 3; ++gt) {
      const int g = gt * 2 + wn;
      const f16x8 bh = ld8h(L + oBh + g * 512 + lane * 8);
      const f16x8 bl = ld8h(L + oBl + g * 512 + lane * 8);
      acc[gt] = __builtin_amdgcn_mfma_f32_16x16x32_f16(ah, bh, acc[gt], 0, 0, 0);
      acc[gt] = __builtin_amdgcn_mfma_f32_16x16x32_f16(ah, bl, acc[gt], 0, 0, 0);
      acc[gt] = __builtin_amdgcn_mfma_f32_16x16x32_f16(al, bh, acc[gt], 0, 0, 0);
    }
    __syncthreads();
  }

  const int c = bn + wn * 16 + lr;
  const float b_ir = bih[c], b_iz = bih[1024 + c], b_in = bih[2048 + c];
  const float b_hr = bhh[c], b_hz = bhh[1024 + c], b_hn = bhh[2048 + c];
  #pragma unroll
  for (int rr = 0; rr < 4; ++rr) {
    const int row = bm + wm * 16 + lg * 4 + rr;
    const size_t gr = (size_t)row * gi_rs;
    const float pr = gi[gr + c]        + b_ir + acc[0][rr] * INVWS + b_hr;
    const float pz = gi[gr + 1024 + c] + b_iz + acc[1][rr] * INVWS + b_hz;
    const float r = 1.f / (1.f + expf(-pr));
    const float z = 1.f / (1.f + expf(-pz));
    const float n = tanhf(gi[gr + 2048 + c] + b_in + r * (acc[2][rr] * INVWS + b_hn));
    const size_t o = (size_t)row * Hsz + c;
    const float h = (1.f - z) * n + z * hf_in[o];
    hf_out[o] = h;
    const f16 hb = (f16)h;
    hho[o] = h2u(hb);
    hlo[o] = h2u((f16)(h - (float)hb));
  }
}

__device__ __forceinline__ void attn_body(
    const float* __restrict__ hf, const float* __restrict__ G,
    const float* __restrict__ c0,
    u32* __restrict__ flag, const u32* __restrict__ valid,
    float* __restrict__ out, int t, int b)
{
  __shared__ float pre_s[32];
  __shared__ float top_s[32];
  const int w = threadIdx.x >> 6;        // 8 waves
  const int lane = threadIdx.x & 63;

  float qr[16];
  const float4* q4 = (const float4*)(hf + (size_t)b * Hsz);
  #pragma unroll
  for (int i = 0; i < 4; ++i) {
    const float4 v = q4[lane * 4 + i];
    qr[4*i+0] = v.x; qr[4*i+1] = v.y; qr[4*i+2] = v.z; qr[4*i+3] = v.w;
  }

  for (int l = w; l < Lsz; l += 8) {
    const float4* r4 = (const float4*)(G + ((size_t)b * Lsz + l) * Hsz);
    float s = 0.f;
    #pragma unroll
    for (int i = 0; i < 4; ++i) {
      const float4 v = r4[lane * 4 + i];
      s = fmaf(qr[4*i+0], v.x, s);
      s = fmaf(qr[4*i+1], v.y, s);
      s = fmaf(qr[4*i+2], v.z, s);
      s = fmaf(qr[4*i+3], v.w, s);
    }
    #pragma unroll
    for (int off = 32; off >= 1; off >>= 1) s += __shfl_xor(s, off, 64);
    if (lane == 0) pre_s[l] = s + c0[b * Lsz + l];
  }
  __syncthreads();

  if (threadIdx.x == 0) {
    const u32 fl = flag[b];
    const u32 ex = fl | ~valid[b];
    float best = -3.4e38f; int am = 0;
    for (int l = 0; l < Lsz; ++l) {
      if (!((ex >> l) & 1u)) { const float v = pre_s[l]; if (v > best) { best = v; am = l; } }
    }
    float sum = 0.f;
    for (int l = 0; l < Lsz; ++l) {
      const float e = ((ex >> l) & 1u) ? 0.f : expf(pre_s[l] - best);
      top_s[l] = e; sum += e;
    }
    const float inv = 1.f / sum;
    for (int l = 0; l < Lsz; ++l) top_s[l] *= inv;
    flag[b] = fl | (1u << am);
  }
  __syncthreads();

  if (threadIdx.x < Lsz) {
    const int l = threadIdx.x;
    out[(size_t)b * (Tsz * Lsz) + t * Lsz + l] = pre_s[l];
    out[(size_t)Bsz * Tsz * Lsz + (size_t)b * (Tsz * Lsz) + t * Lsz + l] = top_s[l];
  }
}

// ghc[0] standalone
__global__ __launch_bounds__(512) void k_ghc0(
    const u16* Hh, const u16* Hl, const u16* Wh, const u16* Wl,
    const float* gi, int gi_rs, const float* bih, const float* bhh,
    const float* hf_in, float* hf_out, u16* hho, u16* hlo)
{
  const int bn = (blockIdx.x & 31) * 32, bm = (blockIdx.x >> 5) * 64;
  ghc_body(Hh, Hl, Wh, Wl, gi, gi_rs, bih, bhh, hf_in, hf_out, hho, hlo, bm, bn);
}

// fused: attn[t] (blocks 256..767) + ghc[t+1] (blocks 0..255, if do_ghc)
__global__ __launch_bounds__(512) void k_step(
    const float* hf_t, const u16* hh_t, const u16* hl_t,
    float* hf_n, u16* hh_n, u16* hl_n,
    const u16* Wh, const u16* Wl,
    const float* gi, const float* bih, const float* bhh,
    const float* G, const float* c0,
    u32* flag, const u32* valid, float* out, int t, int do_ghc)
{
  if (blockIdx.x < 256) {
    if (!do_ghc) return;
    const int bn = (blockIdx.x & 31) * 32, bm = (blockIdx.x >> 5) * 64;
    ghc_body(hh_t, hl_t, Wh, Wl, gi, 3072, bih, bhh, hf_t, hf_n, hh_n, hl_n, bm, bn);
  } else {
    attn_body(hf_t, G, c0, flag, valid, out, t, blockIdx.x - 256);
  }
}

extern "C" void kernel_launch(void* const* d_in, const int* in_sizes, int n_in,
                              void* d_out, int out_size, void* d_ws, size_t ws_size,
                              hipStream_t stream) {
  const float* ih  = (const float*)d_in[0];
  const float* tg  = (const float*)d_in[1];
  const int*   pos = (const int*)d_in[2];
  const float* S   = (const float*)d_in[4];
  const float* wih = (const float*)d_in[5];
  const float* whh = (const float*)d_in[6];
  const float* bih = (const float*)d_in[7];
  const float* bhh = (const float*)d_in[8];
  const float* wlw = (const float*)d_in[9];
  const float* wlb = (const float*)d_in[10];
  float* out = (float*)d_out;

  const size_t NW3 = (size_t)3 * Hsz * Hsz;
  const size_t NW1 = (size_t)Hsz * Hsz;
  const size_t NH  = (size_t)Bsz * Hsz;

  char* p = (char*)d_ws;
  u16* wihh = (u16*)p; p += NW3 * 2;
  u16* wihl = (u16*)p; p += NW3 * 2;
  u16* whhh = (u16*)p; p += NW3 * 2;
  u16* whhl = (u16*)p; p += NW3 * 2;
  u16* wlt0 = (u16*)p; p += NW1 * 2;
  u16* wlt1 = (u16*)p; p += NW1 * 2;
  float* ring = (float*)p; p += (size_t)8 * Bsz * 3072 * 4;
  float* G    = (float*)p; p += (size_t)Bsz * Lsz * Hsz * 4;
  float* c0   = (float*)p; p += (size_t)Bsz * Lsz * 4;
  float* gi0  = (float*)p; p += 3072 * 4;
  float* hfb[2]; u16* hhb[2]; u16* hlb[2];
  hfb[0] = (float*)p; p += NH * 4;
  hfb[1] = (float*)p; p += NH * 4;
  hhb[0] = (u16*)p; p += NH * 2;
  hlb[0] = (u16*)p; p += NH * 2;
  hhb[1] = (u16*)p; p += NH * 2;
  hlb[1] = (u16*)p; p += NH * 2;
  u32* flag  = (u32*)p; p += Bsz * 4;
  u32* valid = (u32*)p; p += Bsz * 4;

  k_split<<<(int)(NW3 / 4 + 255) / 256, 256, 0, stream>>>(wih, wihh, wihl, (int)(NW3 / 4));
  k_split<<<(int)(NW3 / 4 + 255) / 256, 256, 0, stream>>>(whh, whhh, whhl, (int)(NW3 / 4));
  k_splitT2<<<dim3(32, 32), 256, 0, stream>>>(wlw, wlt0, wlt1);
  k_init<<<Bsz, 256, 0, stream>>>(ih, pos, wlb, hfb[0], hhb[0], hlb[0], c0, flag, valid);
  k_gemv0<<<48, 256, 0, stream>>>(S, wih, gi0);
  // G = ih @ WlT (M=15360, N=1024), 3-pass fp16, 128^2 dbuf
  k_tgemm<0><<<dim3(8, 120), 256, 0, stream>>>(ih, wlt0, wlt1, G, Hsz, 0);

  // h[0]: ghc with gi0 (stride 0); h0 (mean) in buf0 -> h[0] in buf1
  k_ghc0<<<256, 512, 0, stream>>>(hhb[0], hlb[0], whhh, whhl, gi0, 0, bih, bhh,
                                  hfb[0], hfb[1], hhb[1], hlb[1]);

  for (int t = 0; t < Tsz; ++t) {
    const int tn = t + 1;
    if (tn == 1 || tn == 9 || tn == 17 || tn == 25) {
      const int ns = (tn == 25) ? 5 : 8;
      k_tgemm<1><<<dim3(24, ns * 4), 256, 0, stream>>>(tg, wihh, wihl, ring, 3072, tn);
    }
    const int ci = tn & 1;        // h[t] buffer
    const int ni = t & 1;         // h[t+1] buffer
    const int do_ghc = (t < Tsz - 1) ? 1 : 0;
    k_step<<<768, 512, 0, stream>>>(hfb[ci], hhb[ci], hlb[ci],
                                    hfb[ni], hhb[ni], hlb[ni],
                                    whhh, whhl,
                                    ring + (size_t)(tn & 7) * Bsz * 3072,
                                    bih, bhh, G, c0, flag, valid, out, t, do_ghc);
  }
}